// Round 1
// 746.687 us; speedup vs baseline: 1.1069x; 1.1069x over previous
//
#include <hip/hip_runtime.h>
#include <hip/hip_bf16.h>
#include <math.h>

typedef __bf16 bf16;
typedef __bf16 bf16x8 __attribute__((ext_vector_type(8)));
typedef float f32x4 __attribute__((ext_vector_type(4)));

#define MP    4224      // padded token rows (33*128)
#define MACT  4100      // B*N = 4*1025
#define NQTOK 1025
#define NKTOK 1024
#define EDIM  1024
#define FDIM  4096
#define NHEAD 16
#define HD    64
#define QSCALE 0.125f
#define VTS   1056      // self V^T row stride (16B-aligned, > 1025)

// ---- async global->LDS, 16B per lane; LDS base must be wave-uniform ----
__device__ __forceinline__ void glds16(const bf16* g, bf16* l) {
  __builtin_amdgcn_global_load_lds(
      (const __attribute__((address_space(1))) void*)g,
      (__attribute__((address_space(3))) void*)l, 16, 0, 0);
}

// scalar / 8-wide fp32->bf16 loads (fallback + conversion paths)
__device__ __forceinline__ bf16x8 ld8(const void* p, size_t i, bool f32) {
  if (f32) {
    const float* q = (const float*)p + i;
    bf16x8 r;
#pragma unroll
    for (int j = 0; j < 8; ++j) r[j] = (bf16)q[j];
    return r;
  }
  return *(const bf16x8*)((const bf16*)p + i);
}

// ---- weight/y fp32 -> bf16 pool conversion (one pass per launch) ----
struct WPtrs { const float* s[8]; };
__global__ __launch_bounds__(256) void conv_kernel(WPtrs wp, bf16* dst) {
  const size_t sz[8] = {3145728UL, 1048576UL, 1048576UL, 2097152UL,
                        1048576UL, 4194304UL, 4194304UL, 4194304UL};
  size_t id = ((size_t)blockIdx.x * 256 + threadIdx.x) * 8;
  size_t off = 0;
#pragma unroll
  for (int i = 0; i < 8; ++i) {
    if (id < off + sz[i]) {
      const float* s = wp.s[i] + (id - off);
      bf16x8 r;
#pragma unroll
      for (int j = 0; j < 8; ++j) r[j] = (bf16)s[j];
      *(bf16x8*)(dst + id) = r;
      return;
    }
    off += sz[i];
  }
}

// ---------------- zero the pad rows of hln ----------------
__global__ void zero_pads_kernel(bf16* hln) {
  int i = blockIdx.x * 256 + threadIdx.x;
  const int n = (MP - MACT) * EDIM;
  if (i < n) hln[(size_t)MACT * EDIM + i] = (bf16)0.0f;
}

// ---------------- LayerNorm (one block per token) ----------------
template<bool FIRST>
__global__ __launch_bounds__(256) void ln_kernel(const float* __restrict__ src,
    float* __restrict__ xf, bf16* __restrict__ out,
    const float* __restrict__ g, const float* __restrict__ bta) {
  const int row = blockIdx.x;
  const int tid = threadIdx.x;
  float v[4];
#pragma unroll
  for (int i = 0; i < 4; ++i) {
    v[i] = src[(size_t)row * EDIM + tid + i * 256];
    if (FIRST) xf[(size_t)row * EDIM + tid + i * 256] = v[i];
  }
  float s = 0.f, sq = 0.f;
#pragma unroll
  for (int i = 0; i < 4; ++i) { s += v[i]; sq += v[i] * v[i]; }
#pragma unroll
  for (int m = 32; m >= 1; m >>= 1) {
    s += __shfl_xor(s, m);
    sq += __shfl_xor(sq, m);
  }
  __shared__ float ss[4], ssq[4];
  const int wave = tid >> 6;
  if ((tid & 63) == 0) { ss[wave] = s; ssq[wave] = sq; }
  __syncthreads();
  s = ss[0] + ss[1] + ss[2] + ss[3];
  sq = ssq[0] + ssq[1] + ssq[2] + ssq[3];
  const float mean = s * (1.f / EDIM);
  const float var = sq * (1.f / EDIM) - mean * mean;
  const float rstd = rsqrtf(var + 1e-5f);
#pragma unroll
  for (int i = 0; i < 4; ++i) {
    int e = tid + i * 256;
    out[(size_t)row * EDIM + e] = (bf16)((v[i] - mean) * rstd * g[e] + bta[e]);
  }
}

// ---------------- FC2 combine: outf = xf + g3*(p0 + p1 + bias) ------------
__global__ __launch_bounds__(256) void fc2_reduce_kernel(
    const float* __restrict__ p0, const float* __restrict__ xf,
    const float* __restrict__ bias, const float* __restrict__ gamma,
    float* __restrict__ outf) {
  size_t i = ((size_t)blockIdx.x * 256 + threadIdx.x) * 4;
  if (i >= (size_t)MACT * EDIM) return;
  f32x4 a = *(const f32x4*)(p0 + i);
  f32x4 b = *(const f32x4*)(outf + i);
  f32x4 x = *(const f32x4*)(xf + i);
  const int gn = (int)(i & (EDIM - 1));
  f32x4 r;
#pragma unroll
  for (int j = 0; j < 4; ++j)
    r[j] = x[j] + gamma[gn + j] * (a[j] + b[j] + bias[gn + j]);
  *(f32x4*)(outf + i) = r;
}

// ---------------- GEMM: C[m,n] = sum_k A[m,k]*B[n,k], fused epilogues ----
// V outputs are written TRANSPOSED in global: V^T[(b,h,d), key].
enum { EPI_QKV = 0, EPI_KV = 1, EPI_Q = 2, EPI_RES = 3, EPI_GELU = 4,
       EPI_FINAL = 5, EPI_PART = 6 };

template<int EPI, bool ASY>
__global__ __launch_bounds__(256) void gemm_bt(
    const void* __restrict__ A, const void* __restrict__ Bw,
    int K, int Kc,
    const float* __restrict__ bias0, const float* __restrict__ bias1,
    const float* __restrict__ gamma, float* __restrict__ xf,
    bf16* __restrict__ out0, bf16* __restrict__ out1, bf16* __restrict__ out2,
    float* __restrict__ outf)
{
  constexpr int LDP = ASY ? 32 : 40;   // async needs contiguous rows (no pad)
  __shared__ bf16 As[128][LDP];
  __shared__ bf16 Bs[128][LDP];
  const int tid = threadIdx.x;
  const int lane = tid & 63, wave = tid >> 6;
  const int quad = lane >> 4, l16 = lane & 15;
  const int wr = wave >> 1, wc = wave & 1;
  const int m0 = blockIdx.y * 128, n0 = blockIdx.x * 128;
  const int kbase = blockIdx.z * Kc;
  const bool first = (blockIdx.z == 0);
  const int r0 = tid >> 2, c0 = (tid & 3) * 8;

  const bf16* gA = nullptr; const bf16* gB = nullptr;
  bf16* lA = nullptr; bf16* lB = nullptr;
  if (ASY) {
    gA = (const bf16*)A + (size_t)(m0 + wave * 16 + (lane >> 2)) * K + kbase + (lane & 3) * 8;
    gB = (const bf16*)Bw + (size_t)(n0 + wave * 16 + (lane >> 2)) * K + kbase + (lane & 3) * 8;
    lA = &As[wave * 16][0];
    lB = &Bs[wave * 16][0];
  }

  f32x4 acc[4][4];
#pragma unroll
  for (int i = 0; i < 4; ++i)
#pragma unroll
    for (int j = 0; j < 4; ++j)
#pragma unroll
      for (int r = 0; r < 4; ++r) acc[i][j][r] = 0.f;

  for (int k0 = 0; k0 < Kc; k0 += 32) {
    if (ASY) {
      glds16(gA, lA);
      glds16(gA + (size_t)64 * K, lA + 64 * 32);
      glds16(gB, lB);
      glds16(gB + (size_t)64 * K, lB + 64 * 32);
      gA += 32; gB += 32;
    } else {
      const bool f32a = (EPI == EPI_KV);   // fallback: y fp32, weights fp32
      const size_t kk = (size_t)(kbase + k0);
      *(bf16x8*)(&As[r0][c0])      = ld8(A,  (size_t)(m0 + r0) * K + kk + c0, f32a);
      *(bf16x8*)(&As[r0 + 64][c0]) = ld8(A,  (size_t)(m0 + r0 + 64) * K + kk + c0, f32a);
      *(bf16x8*)(&Bs[r0][c0])      = ld8(Bw, (size_t)(n0 + r0) * K + kk + c0, true);
      *(bf16x8*)(&Bs[r0 + 64][c0]) = ld8(Bw, (size_t)(n0 + r0 + 64) * K + kk + c0, true);
    }
    __syncthreads();
    bf16x8 af[4], bfv[4];
#pragma unroll
    for (int i = 0; i < 4; ++i) {
      af[i]  = *(const bf16x8*)(&As[wr * 64 + i * 16 + l16][quad * 8]);
      bfv[i] = *(const bf16x8*)(&Bs[wc * 64 + i * 16 + l16][quad * 8]);
    }
#pragma unroll
    for (int mb = 0; mb < 4; ++mb)
#pragma unroll
      for (int nb = 0; nb < 4; ++nb)
        acc[mb][nb] = __builtin_amdgcn_mfma_f32_16x16x32_bf16(af[mb], bfv[nb], acc[mb][nb], 0, 0, 0);
    __syncthreads();
  }

  // epilogue
#pragma unroll
  for (int mb = 0; mb < 4; ++mb) {
#pragma unroll
    for (int r = 0; r < 4; ++r) {
      const int gm = m0 + wr * 64 + mb * 16 + quad * 4 + r;
#pragma unroll
      for (int nb = 0; nb < 4; ++nb) {
        const int gn = n0 + wc * 64 + nb * 16 + l16;
        float v = acc[mb][nb][r];
        if (EPI == EPI_QKV) {
          if (gm < MACT) {
            unsigned b = (unsigned)gm / 1025u;
            unsigned t = (unsigned)gm - b * 1025u;
            int sec = gn >> 10, e = gn & 1023;
            int h = e >> 6, d = e & 63;
            if (sec == 0)
              out0[((size_t)(b * NHEAD + h) * NQTOK + t) * HD + d] =
                  (bf16)((v + bias0[e]) * QSCALE);
            else if (sec == 1)
              out1[((size_t)(b * NHEAD + h) * NQTOK + t) * HD + d] = (bf16)v;
            else   // V transposed: row = d, col = token
              out2[((size_t)(b * NHEAD + h) * HD + d) * VTS + t] =
                  (bf16)(v + bias1[e]);
          }
        } else if (EPI == EPI_KV) {
          unsigned b = (unsigned)gm >> 10;
          unsigned t = (unsigned)gm & 1023u;
          int sec = gn >> 10, e = gn & 1023;
          int h = e >> 6, d = e & 63;
          if (sec == 0)
            out0[((size_t)(b * NHEAD + h) * NKTOK + t) * HD + d] = (bf16)v;
          else   // V transposed, stride NKTOK (1024, aligned)
            out1[((size_t)(b * NHEAD + h) * HD + d) * NKTOK + t] =
                (bf16)(v + bias1[e]);
        } else if (EPI == EPI_Q) {
          // single K-chunk (z=1): plain store, no atomics, no memset needed
          if (gm < MACT) {
            unsigned b = (unsigned)gm / 1025u;
            unsigned t = (unsigned)gm - b * 1025u;
            int h = gn >> 6, d = gn & 63;
            outf[((size_t)(b * NHEAD + h) * NQTOK + t) * HD + d] =
                (v + bias0[gn]) * QSCALE;
          }
        } else if (EPI == EPI_RES) {
          // single K-chunk (z=1): single writer -> plain RMW, no atomics
          if (gm < MACT) {
            size_t o = (size_t)gm * EDIM + gn;
            xf[o] += gamma[gn] * (v + bias0[gn]);
          }
        } else if (EPI == EPI_GELU) {
          float z = v + bias0[gn];
          float ge = 0.5f * z * (1.0f + erff(z * 0.70710678118f));
          out0[(size_t)gm * FDIM + gn] = (bf16)ge;
        } else if (EPI == EPI_PART) {
          // split-K=2 partials: z=0 -> xf (scratch p0), z=1 -> outf. Plain stores.
          if (gm < MACT) {
            float* dst = first ? xf : outf;
            dst[(size_t)gm * EDIM + gn] = v;
          }
        } else { // EPI_FINAL: fallback path only (d_out f32, zeroed before launch)
          if (gm < MACT) {
            size_t o = (size_t)gm * EDIM + gn;
            float add = gamma[gn] * (v + (first ? bias0[gn] : 0.f));
            if (first) add += xf[o];
            atomicAdd(&outf[o], add);
          }
        }
      }
    }
  }
}

// ---------------- Flash attention (self: causal+rpb, cross: rpb) --------
// grid (17, H, B), block 256 = 4 waves; 64-query tile, 64-key chunks.
// V arrives TRANSPOSED from the producer GEMM -> conflict-free b128 staging.
// K/V global loads software-pipelined one chunk ahead (regs), 2 barriers/chunk.
template<bool CROSS>
__global__ __launch_bounds__(256) void attn_kernel(
    const void* __restrict__ Q, const bf16* __restrict__ Kg,
    const bf16* __restrict__ Vg, const float* __restrict__ rpb,
    bf16* __restrict__ out)
{
  const int NK  = CROSS ? NKTOK : NQTOK;
  const int NRD = CROSS ? 3970 : 3972;
  const int VS  = CROSS ? NKTOK : VTS;     // V^T row stride
  const int qt  = CROSS ? blockIdx.x : (16 - blockIdx.x);  // heavy blocks first
  const int h = blockIdx.y, b = blockIdx.z;
  const int tid = threadIdx.x;
  const int lane = tid & 63, wave = tid >> 6;
  const int quad = lane >> 4, l16 = lane & 15;

  __shared__ bf16 rpb_s[4096];
  __shared__ bf16 Ks[64][72];
  __shared__ bf16 Vt[64][72];        // V^T tile: [d][key]
  __shared__ bf16 Ps[4][16][72];     // per-wave P round-trip

  for (int i = tid; i < 4096; i += 256)
    rpb_s[i] = (bf16)((i < NRD) ? rpb[(size_t)i * NHEAD + h] : 0.f);

  const int q0 = qt * 64;
  const int qrow = q0 + wave * 16 + l16;
  const size_t qhb = (size_t)(b * NHEAD + h) * NQTOK;
  bf16x8 qf0, qf1;
  if (qrow < NQTOK) {
    if (CROSS) {
      const float* Qf = (const float*)Q + (qhb + qrow) * HD;
#pragma unroll
      for (int j = 0; j < 8; ++j) {
        qf0[j] = (bf16)Qf[quad * 8 + j];
        qf1[j] = (bf16)Qf[32 + quad * 8 + j];
      }
    } else {
      const bf16* Qb = (const bf16*)Q;
      qf0 = *(const bf16x8*)(Qb + (qhb + qrow) * HD + quad * 8);
      qf1 = *(const bf16x8*)(Qb + (qhb + qrow) * HD + 32 + quad * 8);
    }
  } else {
#pragma unroll
    for (int j = 0; j < 8; ++j) { qf0[j] = (bf16)0.f; qf1[j] = (bf16)0.f; }
  }

  // hoisted rpb row codes: idx = qcode[r] - kcode for interior pixels
  int qgv[4], qcode[4];
#pragma unroll
  for (int r = 0; r < 4; ++r) {
    int qg = q0 + wave * 16 + quad * 4 + r;
    qgv[r] = qg;
    int p = qg - 1;
    qcode[r] = (qg > 0) ? ((p >> 5) * 63 + (p & 31) + 1984) : 0;
  }

  float m_run[4], l_run[4];
  f32x4 oacc[4];
#pragma unroll
  for (int r = 0; r < 4; ++r) { m_run[r] = -1e30f; l_run[r] = 0.f; }
#pragma unroll
  for (int d = 0; d < 4; ++d)
#pragma unroll
    for (int r = 0; r < 4; ++r) oacc[d][r] = 0.f;

  const size_t kvbK = (size_t)(b * NHEAD + h) * NK;
  const size_t vbase = (size_t)(b * NHEAD + h) * HD;
  const int nch = CROSS ? (NKTOK / 64) : (qt + 1);

  const int rr = tid >> 3;            // 0..31 (+32 with vv)
  const int co = (tid & 7) * 8;

  bf16x8 krg[2], vrg[2];
  auto stage_load = [&](int c) {
    const int kc = c * 64;
#pragma unroll
    for (int vv = 0; vv < 2; ++vv) {
      const int row = rr + vv * 32;
      // K: natural layout row=key
      if (!CROSS && kc + row >= NK) {
#pragma unroll
        for (int j = 0; j < 8; ++j) krg[vv][j] = (bf16)0.f;
      } else {
        krg[vv] = *(const bf16x8*)(Kg + (kvbK + kc + row) * HD + co);
      }
      // V^T: row=d, col=key
      if (!CROSS && kc + co >= NK) {
#pragma unroll
        for (int j = 0; j < 8; ++j) vrg[vv][j] = (bf16)0.f;
      } else {
        vrg[vv] = *(const bf16x8*)(Vg + (vbase + row) * VS + kc + co);
      }
    }
  };

  stage_load(0);
  for (int c = 0; c < nch; ++c) {
    const int kc = c * 64;
    if (c) __syncthreads();
#pragma unroll
    for (int vv = 0; vv < 2; ++vv) {
      const int row = rr + vv * 32;
      *(bf16x8*)(&Ks[row][co]) = krg[vv];
      *(bf16x8*)(&Vt[row][co]) = vrg[vv];
    }
    __syncthreads();
    if (c + 1 < nch) stage_load(c + 1);   // prefetch overlaps compute

    // ---- S = Q K^T + bias (+causal) ----
    float sv[4][4];
#pragma unroll
    for (int kb = 0; kb < 4; ++kb) {
      f32x4 a;
#pragma unroll
      for (int r = 0; r < 4; ++r) a[r] = 0.f;
      bf16x8 kf0 = *(const bf16x8*)(&Ks[kb * 16 + l16][quad * 8]);
      bf16x8 kf1 = *(const bf16x8*)(&Ks[kb * 16 + l16][32 + quad * 8]);
      a = __builtin_amdgcn_mfma_f32_16x16x32_bf16(qf0, kf0, a, 0, 0, 0);
      a = __builtin_amdgcn_mfma_f32_16x16x32_bf16(qf1, kf1, a, 0, 0, 0);
      const int kg = kc + kb * 16 + l16;
      int kcode;
      if (CROSS) kcode = (kg >> 5) * 63 + (kg & 31);
      else {
        int k1 = kg - 1;
        kcode = (kg > 0) ? ((k1 >> 5) * 63 + (k1 & 31)) : 0;
      }
#pragma unroll
      for (int r = 0; r < 4; ++r) {
        const int qg = qgv[r];
        bool valid = (kg < NK) && (CROSS || kg <= qg);
        int idx;
        if (CROSS) {
          idx = (qg == 0) ? 3969 : (qcode[r] - kcode);
        } else {
          idx = (qg == 0) ? ((kg == 0) ? 3971 : 3969)
                          : ((kg == 0) ? 3970 : (qcode[r] - kcode));
        }
        sv[kb][r] = valid ? (a[r] + (float)rpb_s[idx]) : -1e30f;
      }
    }

    // ---- online softmax ----
#pragma unroll
    for (int r = 0; r < 4; ++r) {
      float mx = fmaxf(fmaxf(sv[0][r], sv[1][r]), fmaxf(sv[2][r], sv[3][r]));
#pragma unroll
      for (int mk = 8; mk >= 1; mk >>= 1) mx = fmaxf(mx, __shfl_xor(mx, mk));
      const float mnew = fmaxf(m_run[r], mx);
      const float alpha = __expf(m_run[r] - mnew);
      m_run[r] = mnew;
      float rs = 0.f;
#pragma unroll
      for (int kb = 0; kb < 4; ++kb) {
        float p = __expf(sv[kb][r] - mnew);
        rs += p;
        Ps[wave][quad * 4 + r][kb * 16 + l16] = (bf16)p;
      }
#pragma unroll
      for (int mk = 8; mk >= 1; mk >>= 1) rs += __shfl_xor(rs, mk);
      l_run[r] = l_run[r] * alpha + rs;
#pragma unroll
      for (int d = 0; d < 4; ++d) oacc[d][r] *= alpha;
    }

    // ---- O += P V (Ps round-trip intra-wave; Vt fragments are b128) ----
    bf16x8 pf0 = *(const bf16x8*)(&Ps[wave][l16][quad * 8]);
    bf16x8 pf1 = *(const bf16x8*)(&Ps[wave][l16][32 + quad * 8]);
#pragma unroll
    for (int db = 0; db < 4; ++db) {
      bf16x8 vf0 = *(const bf16x8*)(&Vt[db * 16 + l16][quad * 8]);
      bf16x8 vf1 = *(const bf16x8*)(&Vt[db * 16 + l16][32 + quad * 8]);
      oacc[db] = __builtin_amdgcn_mfma_f32_16x16x32_bf16(pf0, vf0, oacc[db], 0, 0, 0);
      oacc[db] = __builtin_amdgcn_mfma_f32_16x16x32_bf16(pf1, vf1, oacc[db], 0, 0, 0);
    }
  }

  // ---- write O ----
#pragma unroll
  for (int r = 0; r < 4; ++r) {
    const int qg = qgv[r];
    if (qg < NQTOK) {
      const float inv = 1.f / l_run[r];
      const size_t row = (size_t)b * NQTOK + qg;
#pragma unroll
      for (int db = 0; db < 4; ++db)
        out[row * EDIM + h * HD + db * 16 + l16] = (bf16)(oacc[db][r] * inv);
    }
  }
}

// ---------------- launch ----------------
extern "C" void kernel_launch(void* const* d_in, const int* in_sizes, int n_in,
                              void* d_out, int out_size, void* d_ws, size_t ws_size,
                              hipStream_t stream) {
  (void)in_sizes; (void)n_in; (void)out_size;
  const float* x        = (const float*)d_in[0];
  const float* y        = (const float*)d_in[1];
  const float* n1g      = (const float*)d_in[2];
  const float* n1b      = (const float*)d_in[3];
  const float* n2g      = (const float*)d_in[4];
  const float* n2b      = (const float*)d_in[5];
  const float* n3g      = (const float*)d_in[6];
  const float* n3b      = (const float*)d_in[7];
  const float* sa_qkv_w = (const float*)d_in[8];
  const float* sa_qb    = (const float*)d_in[9];
  const float* sa_vb    = (const float*)d_in[10];
  const float* sa_rpb   = (const float*)d_in[11];
  const float* sa_pw    = (const float*)d_in[12];
  const float* sa_pb    = (const float*)d_in[13];
  const float* ca_qw    = (const float*)d_in[14];
  const float* ca_kvw   = (const float*)d_in[15];
  const float* ca_qb    = (const float*)d_in[16];
  const float* ca_vb    = (const float*)d_in[17];
  const float* ca_rpb   = (const float*)d_in[18];
  const float* ca_pw    = (const float*)d_in[19];
  const float* ca_pb    = (const float*)d_in[20];
  const float* fc1_w    = (const float*)d_in[21];
  const float* fc1_b    = (const float*)d_in[22];
  const float* fc2_w    = (const float*)d_in[23];
  const float* fc2_b    = (const float*)d_in[24];
  const float* g1       = (const float*)d_in[25];
  const float* g2       = (const float*)d_in[26];
  const float* g3       = (const float*)d_in[27];
  float* outf = (float*)d_out;     // f32 output; also cross-attn Q scratch
  float* qtf  = (float*)d_out;

  // Workspace: xf(16.9M) | hln(8.7M) | h1-union(34.6M) | bf16 pool(41.9M)
  char* w = (char*)d_ws;
  float* xf = (float*)w;  w += (size_t)MP * EDIM * 4;
  bf16* hln = (bf16*)w;   w += (size_t)MP * EDIM * 2;
  char* big = w;          w += (size_t)MP * FDIM * 2;
  const size_t qkv_sz = (size_t)4 * NHEAD * NQTOK * HD * 2;       // 8.40 MB
  bf16* qt = (bf16*)big;
  bf16* kt = (bf16*)(big + qkv_sz);
  bf16* vt = (bf16*)(big + 2 * qkv_sz);   // V^T (8.65M self; union has room)
  bf16* h1 = (bf16*)big;
  bf16* wpool = (bf16*)w; w += 20971520UL * 2;
  const bool asy = ((size_t)(w - (char*)d_ws) <= ws_size);

  bf16* qkvw_b = wpool;
  bf16* pw_b   = qkvw_b + 3145728UL;
  bf16* cqw_b  = pw_b   + 1048576UL;
  bf16* ckvw_b = cqw_b  + 1048576UL;
  bf16* cpw_b  = ckvw_b + 2097152UL;
  bf16* fc1w_b = cpw_b  + 1048576UL;
  bf16* fc2w_b = fc1w_b + 4194304UL;
  bf16* y_b    = fc2w_b + 4194304UL;
  // FC2 split-K partial (z=0): 16.8 MB over the front of wpool. By FFN time
  // only fc2w_b (at +24 MB) is still live; overlapped weights are dead
  // (stream-ordered: EPI_GELU's read of fc1w_b completes before EPI_PART).
  float* part0 = (float*)wpool;

  if (asy) {
    WPtrs wp = {{sa_qkv_w, sa_pw, ca_qw, ca_kvw, ca_pw, fc1_w, fc2_w, y}};
    conv_kernel<<<10240, 256, 0, stream>>>(wp, wpool);
  }
  zero_pads_kernel<<<dim3(((MP - MACT) * EDIM + 255) / 256), 256, 0, stream>>>(hln);

  // --- self-attention block ---
  ln_kernel<true><<<MACT, 256, 0, stream>>>(x, xf, hln, n1g, n1b);
  if (asy) gemm_bt<EPI_QKV, true><<<dim3(24, 33, 1), 256, 0, stream>>>(hln, qkvw_b, 1024, 1024,
      sa_qb, sa_vb, nullptr, nullptr, qt, kt, vt, nullptr);
  else     gemm_bt<EPI_QKV, false><<<dim3(24, 33, 1), 256, 0, stream>>>(hln, sa_qkv_w, 1024, 1024,
      sa_qb, sa_vb, nullptr, nullptr, qt, kt, vt, nullptr);
  attn_kernel<false><<<dim3(17, NHEAD, 4), 256, 0, stream>>>(qt, kt, vt, sa_rpb, hln);
  if (asy) gemm_bt<EPI_RES, true><<<dim3(8, 33, 1), 256, 0, stream>>>(hln, pw_b, 1024, 1024,
      sa_pb, nullptr, g1, xf, nullptr, nullptr, nullptr, nullptr);
  else     gemm_bt<EPI_RES, false><<<dim3(8, 33, 1), 256, 0, stream>>>(hln, sa_pw, 1024, 1024,
      sa_pb, nullptr, g1, xf, nullptr, nullptr, nullptr, nullptr);

  // --- cross-attention block ---
  ln_kernel<false><<<MACT, 256, 0, stream>>>(xf, nullptr, hln, n2g, n2b);
  if (asy) gemm_bt<EPI_Q, true><<<dim3(8, 33, 1), 256, 0, stream>>>(hln, cqw_b, 1024, 1024,
      ca_qb, nullptr, nullptr, nullptr, nullptr, nullptr, nullptr, qtf);
  else     gemm_bt<EPI_Q, false><<<dim3(8, 33, 1), 256, 0, stream>>>(hln, ca_qw, 1024, 1024,
      ca_qb, nullptr, nullptr, nullptr, nullptr, nullptr, nullptr, qtf);
  if (asy) gemm_bt<EPI_KV, true><<<dim3(16, 32, 1), 256, 0, stream>>>(y_b, ckvw_b, 1024, 1024,
      nullptr, ca_vb, nullptr, nullptr, kt, vt, nullptr, nullptr);
  else     gemm_bt<EPI_KV, false><<<dim3(16, 32, 1), 256, 0, stream>>>(y, ca_kvw, 1024, 1024,
      nullptr, ca_vb, nullptr, nullptr, kt, vt, nullptr, nullptr);
  attn_kernel<true><<<dim3(17, NHEAD, 4), 256, 0, stream>>>(qtf, kt, vt, ca_rpb, hln);  // 17 tiles!
  if (asy) gemm_bt<EPI_RES, true><<<dim3(8, 33, 1), 256, 0, stream>>>(hln, cpw_b, 1024, 1024,
      ca_pb, nullptr, g2, xf, nullptr, nullptr, nullptr, nullptr);
  else     gemm_bt<EPI_RES, false><<<dim3(8, 33, 1), 256, 0, stream>>>(hln, ca_pw, 1024, 1024,
      ca_pb, nullptr, g2, xf, nullptr, nullptr, nullptr, nullptr);

  // --- FFN ---
  ln_kernel<false><<<MACT, 256, 0, stream>>>(xf, nullptr, hln, n3g, n3b);
  if (asy) gemm_bt<EPI_GELU, true><<<dim3(32, 33, 1), 256, 0, stream>>>(hln, fc1w_b, 1024, 1024,
      fc1_b, nullptr, nullptr, nullptr, h1, nullptr, nullptr, nullptr);
  else     gemm_bt<EPI_GELU, false><<<dim3(32, 33, 1), 256, 0, stream>>>(hln, fc1_w, 1024, 1024,
      fc1_b, nullptr, nullptr, nullptr, h1, nullptr, nullptr, nullptr);
  if (asy) {
    // split-K=2, plain partial stores (z=0 -> part0, z=1 -> outf), then combine
    gemm_bt<EPI_PART, true><<<dim3(8, 33, 2), 256, 0, stream>>>(h1, fc2w_b, 4096, 2048,
        nullptr, nullptr, nullptr, part0, nullptr, nullptr, nullptr, outf);
    fc2_reduce_kernel<<<dim3(4100), 256, 0, stream>>>(part0, xf, fc2_b, g3, outf);
  } else {
    hipMemsetAsync(outf, 0, (size_t)MACT * EDIM * 4, stream);  // reset for final
    gemm_bt<EPI_FINAL, false><<<dim3(8, 33, 4), 256, 0, stream>>>(h1, fc2_w, 4096, 1024,
        fc2_b, nullptr, g3, xf, nullptr, nullptr, nullptr, outf);
  }
}

// Round 2
// 719.703 us; speedup vs baseline: 1.1484x; 1.0375x over previous
//
#include <hip/hip_runtime.h>
#include <hip/hip_bf16.h>
#include <math.h>

typedef __bf16 bf16;
typedef __bf16 bf16x8 __attribute__((ext_vector_type(8)));
typedef float f32x4 __attribute__((ext_vector_type(4)));

#define MP    4224      // padded token rows (33*128)
#define MACT  4100      // B*N = 4*1025
#define NQTOK 1025
#define NKTOK 1024
#define EDIM  1024
#define FDIM  4096
#define NHEAD 16
#define HD    64
#define QSCALE 0.125f
#define VTS   1056      // self V^T row stride (16B-aligned, > 1025)

// ---- async global->LDS, 16B per lane; LDS base must be wave-uniform ----
__device__ __forceinline__ void glds16(const bf16* g, bf16* l) {
  __builtin_amdgcn_global_load_lds(
      (const __attribute__((address_space(1))) void*)g,
      (__attribute__((address_space(3))) void*)l, 16, 0, 0);
}

// scalar / 8-wide fp32->bf16 loads (fallback + conversion paths)
__device__ __forceinline__ bf16x8 ld8(const void* p, size_t i, bool f32) {
  if (f32) {
    const float* q = (const float*)p + i;
    bf16x8 r;
#pragma unroll
    for (int j = 0; j < 8; ++j) r[j] = (bf16)q[j];
    return r;
  }
  return *(const bf16x8*)((const bf16*)p + i);
}

// ---- weight/y fp32 -> bf16 pool conversion (one pass per launch) ----
struct WPtrs { const float* s[8]; };
__global__ __launch_bounds__(256) void conv_kernel(WPtrs wp, bf16* dst) {
  const size_t sz[8] = {3145728UL, 1048576UL, 1048576UL, 2097152UL,
                        1048576UL, 4194304UL, 4194304UL, 4194304UL};
  size_t id = ((size_t)blockIdx.x * 256 + threadIdx.x) * 8;
  size_t off = 0;
#pragma unroll
  for (int i = 0; i < 8; ++i) {
    if (id < off + sz[i]) {
      const float* s = wp.s[i] + (id - off);
      bf16x8 r;
#pragma unroll
      for (int j = 0; j < 8; ++j) r[j] = (bf16)s[j];
      *(bf16x8*)(dst + id) = r;
      return;
    }
    off += sz[i];
  }
}

// ---------------- zero the pad rows of hln ----------------
__global__ void zero_pads_kernel(bf16* hln) {
  int i = blockIdx.x * 256 + threadIdx.x;
  const int n = (MP - MACT) * EDIM;
  if (i < n) hln[(size_t)MACT * EDIM + i] = (bf16)0.0f;
}

// ---------------- LayerNorm (one block per token) ----------------
template<bool FIRST>
__global__ __launch_bounds__(256) void ln_kernel(const float* __restrict__ src,
    float* __restrict__ xf, bf16* __restrict__ out,
    const float* __restrict__ g, const float* __restrict__ bta) {
  const int row = blockIdx.x;
  const int tid = threadIdx.x;
  float v[4];
#pragma unroll
  for (int i = 0; i < 4; ++i) {
    v[i] = src[(size_t)row * EDIM + tid + i * 256];
    if (FIRST) xf[(size_t)row * EDIM + tid + i * 256] = v[i];
  }
  float s = 0.f, sq = 0.f;
#pragma unroll
  for (int i = 0; i < 4; ++i) { s += v[i]; sq += v[i] * v[i]; }
#pragma unroll
  for (int m = 32; m >= 1; m >>= 1) {
    s += __shfl_xor(s, m);
    sq += __shfl_xor(sq, m);
  }
  __shared__ float ss[4], ssq[4];
  const int wave = tid >> 6;
  if ((tid & 63) == 0) { ss[wave] = s; ssq[wave] = sq; }
  __syncthreads();
  s = ss[0] + ss[1] + ss[2] + ss[3];
  sq = ssq[0] + ssq[1] + ssq[2] + ssq[3];
  const float mean = s * (1.f / EDIM);
  const float var = sq * (1.f / EDIM) - mean * mean;
  const float rstd = rsqrtf(var + 1e-5f);
#pragma unroll
  for (int i = 0; i < 4; ++i) {
    int e = tid + i * 256;
    out[(size_t)row * EDIM + e] = (bf16)((v[i] - mean) * rstd * g[e] + bta[e]);
  }
}

// ---------------- FC2 combine: outf = xf + g3*(p0 + p1 + bias) ------------
__global__ __launch_bounds__(256) void fc2_reduce_kernel(
    const float* __restrict__ p0, const float* __restrict__ xf,
    const float* __restrict__ bias, const float* __restrict__ gamma,
    float* __restrict__ outf) {
  size_t i = ((size_t)blockIdx.x * 256 + threadIdx.x) * 4;
  if (i >= (size_t)MACT * EDIM) return;
  f32x4 a = *(const f32x4*)(p0 + i);
  f32x4 b = *(const f32x4*)(outf + i);
  f32x4 x = *(const f32x4*)(xf + i);
  const int gn = (int)(i & (EDIM - 1));
  f32x4 r;
#pragma unroll
  for (int j = 0; j < 4; ++j)
    r[j] = x[j] + gamma[gn + j] * (a[j] + b[j] + bias[gn + j]);
  *(f32x4*)(outf + i) = r;
}

// ---------------- GEMM: C[m,n] = sum_k A[m,k]*B[n,k], fused epilogues ----
// V outputs are written TRANSPOSED in global: V^T[(b,h,d), key].
enum { EPI_QKV = 0, EPI_KV = 1, EPI_Q = 2, EPI_RES = 3, EPI_GELU = 4,
       EPI_FINAL = 5, EPI_PART = 6 };

template<int EPI, bool ASY>
__global__ __launch_bounds__(256) void gemm_bt(
    const void* __restrict__ A, const void* __restrict__ Bw,
    int K, int Kc,
    const float* __restrict__ bias0, const float* __restrict__ bias1,
    const float* __restrict__ gamma, float* __restrict__ xf,
    bf16* __restrict__ out0, bf16* __restrict__ out1, bf16* __restrict__ out2,
    float* __restrict__ outf)
{
  constexpr int LDP = ASY ? 32 : 40;   // async needs contiguous rows (no pad)
  __shared__ bf16 As[128][LDP];
  __shared__ bf16 Bs[128][LDP];
  const int tid = threadIdx.x;
  const int lane = tid & 63, wave = tid >> 6;
  const int quad = lane >> 4, l16 = lane & 15;
  const int wr = wave >> 1, wc = wave & 1;
  const int m0 = blockIdx.y * 128, n0 = blockIdx.x * 128;
  const int kbase = blockIdx.z * Kc;
  const bool first = (blockIdx.z == 0);
  const int r0 = tid >> 2, c0 = (tid & 3) * 8;

  const bf16* gA = nullptr; const bf16* gB = nullptr;
  bf16* lA = nullptr; bf16* lB = nullptr;
  if (ASY) {
    gA = (const bf16*)A + (size_t)(m0 + wave * 16 + (lane >> 2)) * K + kbase + (lane & 3) * 8;
    gB = (const bf16*)Bw + (size_t)(n0 + wave * 16 + (lane >> 2)) * K + kbase + (lane & 3) * 8;
    lA = &As[wave * 16][0];
    lB = &Bs[wave * 16][0];
  }

  f32x4 acc[4][4];
#pragma unroll
  for (int i = 0; i < 4; ++i)
#pragma unroll
    for (int j = 0; j < 4; ++j)
#pragma unroll
      for (int r = 0; r < 4; ++r) acc[i][j][r] = 0.f;

  for (int k0 = 0; k0 < Kc; k0 += 32) {
    if (ASY) {
      glds16(gA, lA);
      glds16(gA + (size_t)64 * K, lA + 64 * 32);
      glds16(gB, lB);
      glds16(gB + (size_t)64 * K, lB + 64 * 32);
      gA += 32; gB += 32;
    } else {
      const bool f32a = (EPI == EPI_KV);   // fallback: y fp32, weights fp32
      const size_t kk = (size_t)(kbase + k0);
      *(bf16x8*)(&As[r0][c0])      = ld8(A,  (size_t)(m0 + r0) * K + kk + c0, f32a);
      *(bf16x8*)(&As[r0 + 64][c0]) = ld8(A,  (size_t)(m0 + r0 + 64) * K + kk + c0, f32a);
      *(bf16x8*)(&Bs[r0][c0])      = ld8(Bw, (size_t)(n0 + r0) * K + kk + c0, true);
      *(bf16x8*)(&Bs[r0 + 64][c0]) = ld8(Bw, (size_t)(n0 + r0 + 64) * K + kk + c0, true);
    }
    __syncthreads();
    bf16x8 af[4], bfv[4];
#pragma unroll
    for (int i = 0; i < 4; ++i) {
      af[i]  = *(const bf16x8*)(&As[wr * 64 + i * 16 + l16][quad * 8]);
      bfv[i] = *(const bf16x8*)(&Bs[wc * 64 + i * 16 + l16][quad * 8]);
    }
#pragma unroll
    for (int mb = 0; mb < 4; ++mb)
#pragma unroll
      for (int nb = 0; nb < 4; ++nb)
        acc[mb][nb] = __builtin_amdgcn_mfma_f32_16x16x32_bf16(af[mb], bfv[nb], acc[mb][nb], 0, 0, 0);
    __syncthreads();
  }

  // epilogue
#pragma unroll
  for (int mb = 0; mb < 4; ++mb) {
#pragma unroll
    for (int r = 0; r < 4; ++r) {
      const int gm = m0 + wr * 64 + mb * 16 + quad * 4 + r;
#pragma unroll
      for (int nb = 0; nb < 4; ++nb) {
        const int gn = n0 + wc * 64 + nb * 16 + l16;
        float v = acc[mb][nb][r];
        if (EPI == EPI_QKV) {
          if (gm < MACT) {
            unsigned b = (unsigned)gm / 1025u;
            unsigned t = (unsigned)gm - b * 1025u;
            int sec = gn >> 10, e = gn & 1023;
            int h = e >> 6, d = e & 63;
            if (sec == 0)
              out0[((size_t)(b * NHEAD + h) * NQTOK + t) * HD + d] =
                  (bf16)((v + bias0[e]) * QSCALE);
            else if (sec == 1)
              out1[((size_t)(b * NHEAD + h) * NQTOK + t) * HD + d] = (bf16)v;
            else   // V transposed: row = d, col = token
              out2[((size_t)(b * NHEAD + h) * HD + d) * VTS + t] =
                  (bf16)(v + bias1[e]);
          }
        } else if (EPI == EPI_KV) {
          unsigned b = (unsigned)gm >> 10;
          unsigned t = (unsigned)gm & 1023u;
          int sec = gn >> 10, e = gn & 1023;
          int h = e >> 6, d = e & 63;
          if (sec == 0)
            out0[((size_t)(b * NHEAD + h) * NKTOK + t) * HD + d] = (bf16)v;
          else   // V transposed, stride NKTOK (1024, aligned)
            out1[((size_t)(b * NHEAD + h) * HD + d) * NKTOK + t] =
                (bf16)(v + bias1[e]);
        } else if (EPI == EPI_Q) {
          // single K-chunk (z=1): plain store, no atomics, no memset needed
          if (gm < MACT) {
            unsigned b = (unsigned)gm / 1025u;
            unsigned t = (unsigned)gm - b * 1025u;
            int h = gn >> 6, d = gn & 63;
            outf[((size_t)(b * NHEAD + h) * NQTOK + t) * HD + d] =
                (v + bias0[gn]) * QSCALE;
          }
        } else if (EPI == EPI_RES) {
          // single K-chunk (z=1): single writer -> plain RMW, no atomics
          if (gm < MACT) {
            size_t o = (size_t)gm * EDIM + gn;
            xf[o] += gamma[gn] * (v + bias0[gn]);
          }
        } else if (EPI == EPI_GELU) {
          float z = v + bias0[gn];
          float ge = 0.5f * z * (1.0f + erff(z * 0.70710678118f));
          out0[(size_t)gm * FDIM + gn] = (bf16)ge;
        } else if (EPI == EPI_PART) {
          // split-K=2 partials: z=0 -> xf (scratch p0), z=1 -> outf. Plain stores.
          if (gm < MACT) {
            float* dst = first ? xf : outf;
            dst[(size_t)gm * EDIM + gn] = v;
          }
        } else { // EPI_FINAL: fallback path only (d_out f32, zeroed before launch)
          if (gm < MACT) {
            size_t o = (size_t)gm * EDIM + gn;
            float add = gamma[gn] * (v + (first ? bias0[gn] : 0.f));
            if (first) add += xf[o];
            atomicAdd(&outf[o], add);
          }
        }
      }
    }
  }
}

// ---------------- Flash attention (self: causal+rpb, cross: rpb) --------
// grid (17, H, B), block 256 = 4 waves; 64-query tile, 64-key chunks.
// SWAPPED QK^T: S^T = mfma(K,Q) so each lane owns a full softmax row
// (q = l16): row max/sum are lane-local + 2 shfl_xor; P reaches the PV
// A-frag via 16 conflict-free ds_bpermutes (no Ps LDS buffer).
// T13 defer-max skips the O-rescale when per-chunk max growth <= 8.
template<bool CROSS>
__global__ __launch_bounds__(256) void attn_kernel(
    const void* __restrict__ Q, const bf16* __restrict__ Kg,
    const bf16* __restrict__ Vg, const float* __restrict__ rpb,
    bf16* __restrict__ out)
{
  const int NK  = CROSS ? NKTOK : NQTOK;
  const int NRD = CROSS ? 3970 : 3972;
  const int VS  = CROSS ? NKTOK : VTS;     // V^T row stride
  const int qt  = CROSS ? blockIdx.x : (16 - blockIdx.x);  // heavy blocks first
  const int h = blockIdx.y, b = blockIdx.z;
  const int tid = threadIdx.x;
  const int lane = tid & 63, wave = tid >> 6;
  const int quad = lane >> 4, l16 = lane & 15;

  __shared__ bf16 rpb_s[4096];
  __shared__ bf16 Ks[64][72];
  __shared__ bf16 Vt[64][72];        // V^T tile: [d][key]

  for (int i = tid; i < 4096; i += 256)
    rpb_s[i] = (bf16)((i < NRD) ? rpb[(size_t)i * NHEAD + h] : 0.f);

  const int q0 = qt * 64;
  const int qrow = q0 + wave * 16 + l16;   // this lane's softmax row AND Q frag row
  const size_t qhb = (size_t)(b * NHEAD + h) * NQTOK;
  bf16x8 qf0, qf1;
  if (qrow < NQTOK) {
    if (CROSS) {
      const float* Qf = (const float*)Q + (qhb + qrow) * HD;
#pragma unroll
      for (int j = 0; j < 8; ++j) {
        qf0[j] = (bf16)Qf[quad * 8 + j];
        qf1[j] = (bf16)Qf[32 + quad * 8 + j];
      }
    } else {
      const bf16* Qb = (const bf16*)Q;
      qf0 = *(const bf16x8*)(Qb + (qhb + qrow) * HD + quad * 8);
      qf1 = *(const bf16x8*)(Qb + (qhb + qrow) * HD + 32 + quad * 8);
    }
  } else {
#pragma unroll
    for (int j = 0; j < 8; ++j) { qf0[j] = (bf16)0.f; qf1[j] = (bf16)0.f; }
  }

  // lane-local q code (q = qrow); rpb idx = qcode - kcode for interior pixels
  const int qg = qrow;
  const int qp = qg - 1;
  const int qcode = (qg > 0) ? ((qp >> 5) * 63 + (qp & 31) + 1984) : 0;

  // lane-local softmax state for row q = qrow (identical across the 4 quads)
  float m_run = -1e30f, l_run = 0.f;
  f32x4 oacc[4];                     // [db]: rows q = quad*4+r, cols d
#pragma unroll
  for (int d = 0; d < 4; ++d)
#pragma unroll
    for (int r = 0; r < 4; ++r) oacc[d][r] = 0.f;

  const size_t kvbK = (size_t)(b * NHEAD + h) * NK;
  const size_t vbase = (size_t)(b * NHEAD + h) * HD;
  const int nch = CROSS ? (NKTOK / 64) : (qt + 1);

  const int rr = tid >> 3;            // 0..31 (+32 with vv)
  const int co = (tid & 7) * 8;

  // bpermute source lanes for the P redistribution (loop-invariant)
  const int srcA = (quad & 1) * 32 + l16;   // quads {0,1} or {2,3} base
  const int srcB = srcA + 16;

  bf16x8 krg[2], vrg[2];
  auto stage_load = [&](int c) {
    const int kc = c * 64;
#pragma unroll
    for (int vv = 0; vv < 2; ++vv) {
      const int row = rr + vv * 32;
      // K: natural layout row=key
      if (!CROSS && kc + row >= NK) {
#pragma unroll
        for (int j = 0; j < 8; ++j) krg[vv][j] = (bf16)0.f;
      } else {
        krg[vv] = *(const bf16x8*)(Kg + (kvbK + kc + row) * HD + co);
      }
      // V^T: row=d, col=key
      if (!CROSS && kc + co >= NK) {
#pragma unroll
        for (int j = 0; j < 8; ++j) vrg[vv][j] = (bf16)0.f;
      } else {
        vrg[vv] = *(const bf16x8*)(Vg + (vbase + row) * VS + kc + co);
      }
    }
  };

  stage_load(0);
  for (int c = 0; c < nch; ++c) {
    const int kc = c * 64;
    if (c) __syncthreads();
#pragma unroll
    for (int vv = 0; vv < 2; ++vv) {
      const int row = rr + vv * 32;
      *(bf16x8*)(&Ks[row][co]) = krg[vv];
      *(bf16x8*)(&Vt[row][co]) = vrg[vv];
    }
    __syncthreads();
    if (c + 1 < nch) stage_load(c + 1);   // prefetch overlaps compute

    // ---- S^T = K Q^T (rows = k, cols = q) + bias (+causal) ----
    // lane (quad,l16) holds sv[kb][r] = S[q=qrow][k = kc + kb*16 + quad*4 + r]
    float sv[4][4];
#pragma unroll
    for (int kb = 0; kb < 4; ++kb) {
      f32x4 a;
#pragma unroll
      for (int r = 0; r < 4; ++r) a[r] = 0.f;
      bf16x8 kf0 = *(const bf16x8*)(&Ks[kb * 16 + l16][quad * 8]);
      bf16x8 kf1 = *(const bf16x8*)(&Ks[kb * 16 + l16][32 + quad * 8]);
      a = __builtin_amdgcn_mfma_f32_16x16x32_bf16(kf0, qf0, a, 0, 0, 0);
      a = __builtin_amdgcn_mfma_f32_16x16x32_bf16(kf1, qf1, a, 0, 0, 0);
#pragma unroll
      for (int r = 0; r < 4; ++r) {
        const int kg = kc + kb * 16 + quad * 4 + r;
        int kcode;
        if (CROSS) kcode = (kg >> 5) * 63 + (kg & 31);
        else {
          int k1 = kg - 1;
          kcode = (kg > 0) ? ((k1 >> 5) * 63 + (k1 & 31)) : 0;
        }
        bool valid = CROSS ? true : (kg < NK && kg <= qg);
        int idx;
        if (CROSS) {
          idx = (qg == 0) ? 3969 : (qcode - kcode);
        } else {
          idx = (qg == 0) ? ((kg == 0) ? 3971 : 3969)
                          : ((kg == 0) ? 3970 : (qcode - kcode));
        }
        idx &= 4095;
        sv[kb][r] = valid ? (a[r] + (float)rpb_s[idx]) : -1e30f;
      }
    }

    // ---- online softmax: whole row is lane-local ----
    float mx = sv[0][0];
#pragma unroll
    for (int kb = 0; kb < 4; ++kb)
#pragma unroll
      for (int r = 0; r < 4; ++r) mx = fmaxf(mx, sv[kb][r]);
    mx = fmaxf(mx, __shfl_xor(mx, 16));
    mx = fmaxf(mx, __shfl_xor(mx, 32));

    if (!__all(mx - m_run <= 8.f)) {       // defer-max: rescale rarely
      const float mnew = fmaxf(m_run, mx);
      const float alpha = __expf(m_run - mnew);
      m_run = mnew;
      l_run *= alpha;
      float alr[4];
#pragma unroll
      for (int r = 0; r < 4; ++r) alr[r] = __shfl(alpha, quad * 4 + r);
#pragma unroll
      for (int d = 0; d < 4; ++d)
#pragma unroll
        for (int r = 0; r < 4; ++r) oacc[d][r] *= alr[r];
    }

    float rs = 0.f;
    unsigned pk[4][2];                 // packed bf16 pairs: (r0,r1),(r2,r3)
#pragma unroll
    for (int kb = 0; kb < 4; ++kb) {
      float p0 = __expf(sv[kb][0] - m_run);
      float p1 = __expf(sv[kb][1] - m_run);
      float p2 = __expf(sv[kb][2] - m_run);
      float p3 = __expf(sv[kb][3] - m_run);
      rs += (p0 + p1) + (p2 + p3);
      union { __bf16 h[2]; unsigned u; } w0, w1;
      w0.h[0] = (bf16)p0; w0.h[1] = (bf16)p1;
      w1.h[0] = (bf16)p2; w1.h[1] = (bf16)p3;
      pk[kb][0] = w0.u; pk[kb][1] = w1.u;
    }
    rs += __shfl_xor(rs, 16);
    rs += __shfl_xor(rs, 32);
    l_run += rs;

    // ---- redistribute P -> A-frag via bpermute (no LDS) ----
    // target lane (quad,l16) frag1 word p: k = quad*8+2p  (kb = quad>>1)
    // source lane: ((quad&1)*2 + (p>>1))*16 + l16, word = pk[kb][p&1]
    union { unsigned u[4]; bf16x8 v; } f0, f1;
#pragma unroll
    for (int p = 0; p < 4; ++p) {
      const int src = (p < 2) ? srcA : srcB;
      unsigned a0 = (unsigned)__shfl((int)pk[0][p & 1], src);
      unsigned a1 = (unsigned)__shfl((int)pk[1][p & 1], src);
      unsigned b0 = (unsigned)__shfl((int)pk[2][p & 1], src);
      unsigned b1 = (unsigned)__shfl((int)pk[3][p & 1], src);
      f0.u[p] = (quad < 2) ? a0 : a1;
      f1.u[p] = (quad < 2) ? b0 : b1;
    }

    // ---- O += P V (Vt fragments are b128) ----
#pragma unroll
    for (int db = 0; db < 4; ++db) {
      bf16x8 vf0 = *(const bf16x8*)(&Vt[db * 16 + l16][quad * 8]);
      bf16x8 vf1 = *(const bf16x8*)(&Vt[db * 16 + l16][32 + quad * 8]);
      oacc[db] = __builtin_amdgcn_mfma_f32_16x16x32_bf16(f0.v, vf0, oacc[db], 0, 0, 0);
      oacc[db] = __builtin_amdgcn_mfma_f32_16x16x32_bf16(f1.v, vf1, oacc[db], 0, 0, 0);
    }
  }

  // ---- write O (oacc rows q = q0 + wave*16 + quad*4 + r) ----
#pragma unroll
  for (int r = 0; r < 4; ++r) {
    const int qo = q0 + wave * 16 + quad * 4 + r;
    if (qo < NQTOK) {
      const float inv = 1.f / __shfl(l_run, quad * 4 + r);
      const size_t row = (size_t)b * NQTOK + qo;
#pragma unroll
      for (int db = 0; db < 4; ++db)
        out[row * EDIM + h * HD + db * 16 + l16] = (bf16)(oacc[db][r] * inv);
    }
  }
}

// ---------------- launch ----------------
extern "C" void kernel_launch(void* const* d_in, const int* in_sizes, int n_in,
                              void* d_out, int out_size, void* d_ws, size_t ws_size,
                              hipStream_t stream) {
  (void)in_sizes; (void)n_in; (void)out_size;
  const float* x        = (const float*)d_in[0];
  const float* y        = (const float*)d_in[1];
  const float* n1g      = (const float*)d_in[2];
  const float* n1b      = (const float*)d_in[3];
  const float* n2g      = (const float*)d_in[4];
  const float* n2b      = (const float*)d_in[5];
  const float* n3g      = (const float*)d_in[6];
  const float* n3b      = (const float*)d_in[7];
  const float* sa_qkv_w = (const float*)d_in[8];
  const float* sa_qb    = (const float*)d_in[9];
  const float* sa_vb    = (const float*)d_in[10];
  const float* sa_rpb   = (const float*)d_in[11];
  const float* sa_pw    = (const float*)d_in[12];
  const float* sa_pb    = (const float*)d_in[13];
  const float* ca_qw    = (const float*)d_in[14];
  const float* ca_kvw   = (const float*)d_in[15];
  const float* ca_qb    = (const float*)d_in[16];
  const float* ca_vb    = (const float*)d_in[17];
  const float* ca_rpb   = (const float*)d_in[18];
  const float* ca_pw    = (const float*)d_in[19];
  const float* ca_pb    = (const float*)d_in[20];
  const float* fc1_w    = (const float*)d_in[21];
  const float* fc1_b    = (const float*)d_in[22];
  const float* fc2_w    = (const float*)d_in[23];
  const float* fc2_b    = (const float*)d_in[24];
  const float* g1       = (const float*)d_in[25];
  const float* g2       = (const float*)d_in[26];
  const float* g3       = (const float*)d_in[27];
  float* outf = (float*)d_out;     // f32 output; also cross-attn Q scratch
  float* qtf  = (float*)d_out;

  // Workspace: xf(16.9M) | hln(8.7M) | h1-union(34.6M) | bf16 pool(41.9M)
  char* w = (char*)d_ws;
  float* xf = (float*)w;  w += (size_t)MP * EDIM * 4;
  bf16* hln = (bf16*)w;   w += (size_t)MP * EDIM * 2;
  char* big = w;          w += (size_t)MP * FDIM * 2;
  const size_t qkv_sz = (size_t)4 * NHEAD * NQTOK * HD * 2;       // 8.40 MB
  bf16* qt = (bf16*)big;
  bf16* kt = (bf16*)(big + qkv_sz);
  bf16* vt = (bf16*)(big + 2 * qkv_sz);   // V^T (8.65M self; union has room)
  bf16* h1 = (bf16*)big;
  bf16* wpool = (bf16*)w; w += 20971520UL * 2;
  const bool asy = ((size_t)(w - (char*)d_ws) <= ws_size);

  bf16* qkvw_b = wpool;
  bf16* pw_b   = qkvw_b + 3145728UL;
  bf16* cqw_b  = pw_b   + 1048576UL;
  bf16* ckvw_b = cqw_b  + 1048576UL;
  bf16* cpw_b  = ckvw_b + 2097152UL;
  bf16* fc1w_b = cpw_b  + 1048576UL;
  bf16* fc2w_b = fc1w_b + 4194304UL;
  bf16* y_b    = fc2w_b + 4194304UL;
  // FC2 split-K partial (z=0): 16.8 MB over the front of wpool. By FFN time
  // only fc2w_b (at +24 MB) is still live; overlapped weights are dead
  // (stream-ordered: EPI_GELU's read of fc1w_b completes before EPI_PART).
  float* part0 = (float*)wpool;

  if (asy) {
    WPtrs wp = {{sa_qkv_w, sa_pw, ca_qw, ca_kvw, ca_pw, fc1_w, fc2_w, y}};
    conv_kernel<<<10240, 256, 0, stream>>>(wp, wpool);
  }
  zero_pads_kernel<<<dim3(((MP - MACT) * EDIM + 255) / 256), 256, 0, stream>>>(hln);

  // --- self-attention block ---
  ln_kernel<true><<<MACT, 256, 0, stream>>>(x, xf, hln, n1g, n1b);
  if (asy) gemm_bt<EPI_QKV, true><<<dim3(24, 33, 1), 256, 0, stream>>>(hln, qkvw_b, 1024, 1024,
      sa_qb, sa_vb, nullptr, nullptr, qt, kt, vt, nullptr);
  else     gemm_bt<EPI_QKV, false><<<dim3(24, 33, 1), 256, 0, stream>>>(hln, sa_qkv_w, 1024, 1024,
      sa_qb, sa_vb, nullptr, nullptr, qt, kt, vt, nullptr);
  attn_kernel<false><<<dim3(17, NHEAD, 4), 256, 0, stream>>>(qt, kt, vt, sa_rpb, hln);
  if (asy) gemm_bt<EPI_RES, true><<<dim3(8, 33, 1), 256, 0, stream>>>(hln, pw_b, 1024, 1024,
      sa_pb, nullptr, g1, xf, nullptr, nullptr, nullptr, nullptr);
  else     gemm_bt<EPI_RES, false><<<dim3(8, 33, 1), 256, 0, stream>>>(hln, sa_pw, 1024, 1024,
      sa_pb, nullptr, g1, xf, nullptr, nullptr, nullptr, nullptr);

  // --- cross-attention block ---
  ln_kernel<false><<<MACT, 256, 0, stream>>>(xf, nullptr, hln, n2g, n2b);
  if (asy) gemm_bt<EPI_Q, true><<<dim3(8, 33, 1), 256, 0, stream>>>(hln, cqw_b, 1024, 1024,
      ca_qb, nullptr, nullptr, nullptr, nullptr, nullptr, nullptr, qtf);
  else     gemm_bt<EPI_Q, false><<<dim3(8, 33, 1), 256, 0, stream>>>(hln, ca_qw, 1024, 1024,
      ca_qb, nullptr, nullptr, nullptr, nullptr, nullptr, nullptr, qtf);
  if (asy) gemm_bt<EPI_KV, true><<<dim3(16, 32, 1), 256, 0, stream>>>(y_b, ckvw_b, 1024, 1024,
      nullptr, ca_vb, nullptr, nullptr, kt, vt, nullptr, nullptr);
  else     gemm_bt<EPI_KV, false><<<dim3(16, 32, 1), 256, 0, stream>>>(y, ca_kvw, 1024, 1024,
      nullptr, ca_vb, nullptr, nullptr, kt, vt, nullptr, nullptr);
  attn_kernel<true><<<dim3(17, NHEAD, 4), 256, 0, stream>>>(qtf, kt, vt, ca_rpb, hln);  // 17 tiles!
  if (asy) gemm_bt<EPI_RES, true><<<dim3(8, 33, 1), 256, 0, stream>>>(hln, cpw_b, 1024, 1024,
      ca_pb, nullptr, g2, xf, nullptr, nullptr, nullptr, nullptr);
  else     gemm_bt<EPI_RES, false><<<dim3(8, 33, 1), 256, 0, stream>>>(hln, ca_pw, 1024, 1024,
      ca_pb, nullptr, g2, xf, nullptr, nullptr, nullptr, nullptr);

  // --- FFN ---
  ln_kernel<false><<<MACT, 256, 0, stream>>>(xf, nullptr, hln, n3g, n3b);
  if (asy) gemm_bt<EPI_GELU, true><<<dim3(32, 33, 1), 256, 0, stream>>>(hln, fc1w_b, 1024, 1024,
      fc1_b, nullptr, nullptr, nullptr, h1, nullptr, nullptr, nullptr);
  else     gemm_bt<EPI_GELU, false><<<dim3(32, 33, 1), 256, 0, stream>>>(hln, fc1_w, 1024, 1024,
      fc1_b, nullptr, nullptr, nullptr, h1, nullptr, nullptr, nullptr);
  if (asy) {
    // split-K=2, plain partial stores (z=0 -> part0, z=1 -> outf), then combine
    gemm_bt<EPI_PART, true><<<dim3(8, 33, 2), 256, 0, stream>>>(h1, fc2w_b, 4096, 2048,
        nullptr, nullptr, nullptr, part0, nullptr, nullptr, nullptr, outf);
    fc2_reduce_kernel<<<dim3(4100), 256, 0, stream>>>(part0, xf, fc2_b, g3, outf);
  } else {
    hipMemsetAsync(outf, 0, (size_t)MACT * EDIM * 4, stream);  // reset for final
    gemm_bt<EPI_FINAL, false><<<dim3(8, 33, 4), 256, 0, stream>>>(h1, fc2_w, 4096, 1024,
        fc2_b, nullptr, g3, xf, nullptr, nullptr, nullptr, outf);
  }
}

// Round 4
// 678.505 us; speedup vs baseline: 1.2181x; 1.0607x over previous
//
#include <hip/hip_runtime.h>
#include <hip/hip_bf16.h>
#include <math.h>

typedef __bf16 bf16;
typedef __bf16 bf16x8 __attribute__((ext_vector_type(8)));
typedef float f32x4 __attribute__((ext_vector_type(4)));

#define MP    4224      // padded token rows (33*128)
#define MACT  4100      // B*N = 4*1025
#define NQTOK 1025
#define NKTOK 1024
#define EDIM  1024
#define FDIM  4096
#define NHEAD 16
#define HD    64
#define QSCALE 0.125f
#define VTS   1056      // self V^T row stride (16B-aligned, > 1025)

// ---- async global->LDS, 16B per lane; LDS base must be wave-uniform ----
__device__ __forceinline__ void glds16(const bf16* g, bf16* l) {
  __builtin_amdgcn_global_load_lds(
      (const __attribute__((address_space(1))) void*)g,
      (__attribute__((address_space(3))) void*)l, 16, 0, 0);
}

// scalar / 8-wide fp32->bf16 loads (fallback + conversion paths)
__device__ __forceinline__ bf16x8 ld8(const void* p, size_t i, bool f32) {
  if (f32) {
    const float* q = (const float*)p + i;
    bf16x8 r;
#pragma unroll
    for (int j = 0; j < 8; ++j) r[j] = (bf16)q[j];
    return r;
  }
  return *(const bf16x8*)((const bf16*)p + i);
}

// ---- weight/y fp32 -> bf16 pool conversion (one pass per launch) ----
struct WPtrs { const float* s[8]; };
__global__ __launch_bounds__(256) void conv_kernel(WPtrs wp, bf16* dst) {
  const size_t sz[8] = {3145728UL, 1048576UL, 1048576UL, 2097152UL,
                        1048576UL, 4194304UL, 4194304UL, 4194304UL};
  size_t id = ((size_t)blockIdx.x * 256 + threadIdx.x) * 8;
  size_t off = 0;
#pragma unroll
  for (int i = 0; i < 8; ++i) {
    if (id < off + sz[i]) {
      const float* s = wp.s[i] + (id - off);
      bf16x8 r;
#pragma unroll
      for (int j = 0; j < 8; ++j) r[j] = (bf16)s[j];
      *(bf16x8*)(dst + id) = r;
      return;
    }
    off += sz[i];
  }
}

// ---------------- zero the pad rows of hln ----------------
__global__ void zero_pads_kernel(bf16* hln) {
  int i = blockIdx.x * 256 + threadIdx.x;
  const int n = (MP - MACT) * EDIM;
  if (i < n) hln[(size_t)MACT * EDIM + i] = (bf16)0.0f;
}

// ---------------- LayerNorm (one block per token) ----------------
template<bool FIRST>
__global__ __launch_bounds__(256) void ln_kernel(const float* __restrict__ src,
    float* __restrict__ xf, bf16* __restrict__ out,
    const float* __restrict__ g, const float* __restrict__ bta) {
  const int row = blockIdx.x;
  const int tid = threadIdx.x;
  float v[4];
#pragma unroll
  for (int i = 0; i < 4; ++i) {
    v[i] = src[(size_t)row * EDIM + tid + i * 256];
    if (FIRST) xf[(size_t)row * EDIM + tid + i * 256] = v[i];
  }
  float s = 0.f, sq = 0.f;
#pragma unroll
  for (int i = 0; i < 4; ++i) { s += v[i]; sq += v[i] * v[i]; }
#pragma unroll
  for (int m = 32; m >= 1; m >>= 1) {
    s += __shfl_xor(s, m);
    sq += __shfl_xor(sq, m);
  }
  __shared__ float ss[4], ssq[4];
  const int wave = tid >> 6;
  if ((tid & 63) == 0) { ss[wave] = s; ssq[wave] = sq; }
  __syncthreads();
  s = ss[0] + ss[1] + ss[2] + ss[3];
  sq = ssq[0] + ssq[1] + ssq[2] + ssq[3];
  const float mean = s * (1.f / EDIM);
  const float var = sq * (1.f / EDIM) - mean * mean;
  const float rstd = rsqrtf(var + 1e-5f);
#pragma unroll
  for (int i = 0; i < 4; ++i) {
    int e = tid + i * 256;
    out[(size_t)row * EDIM + e] = (bf16)((v[i] - mean) * rstd * g[e] + bta[e]);
  }
}

// ---------------- FC2 combine: outf = xf + g3*(p0 + p1 + bias) ------------
__global__ __launch_bounds__(256) void fc2_reduce_kernel(
    const float* __restrict__ p0, const float* __restrict__ xf,
    const float* __restrict__ bias, const float* __restrict__ gamma,
    float* __restrict__ outf) {
  size_t i = ((size_t)blockIdx.x * 256 + threadIdx.x) * 4;
  if (i >= (size_t)MACT * EDIM) return;
  f32x4 a = *(const f32x4*)(p0 + i);
  f32x4 b = *(const f32x4*)(outf + i);
  f32x4 x = *(const f32x4*)(xf + i);
  const int gn = (int)(i & (EDIM - 1));
  f32x4 r;
#pragma unroll
  for (int j = 0; j < 4; ++j)
    r[j] = x[j] + gamma[gn + j] * (a[j] + b[j] + bias[gn + j]);
  *(f32x4*)(outf + i) = r;
}

// ---------------- GEMM: C[m,n] = sum_k A[m,k]*B[n,k], fused epilogues ----
// Double-buffered LDS, 2-phase pattern: stage(next) issued BEFORE compute(cur),
// ONE barrier per K-step. V outputs written TRANSPOSED: V^T[(b,h,d), key].
enum { EPI_QKV = 0, EPI_KV = 1, EPI_Q = 2, EPI_RES = 3, EPI_GELU = 4,
       EPI_FINAL = 5, EPI_PART = 6 };

template<int EPI, bool ASY>
__global__ __launch_bounds__(256) void gemm_bt(
    const void* __restrict__ A, const void* __restrict__ Bw,
    int K, int Kc,
    const float* __restrict__ bias0, const float* __restrict__ bias1,
    const float* __restrict__ gamma, float* __restrict__ xf,
    bf16* __restrict__ out0, bf16* __restrict__ out1, bf16* __restrict__ out2,
    float* __restrict__ outf)
{
  constexpr int LDP = ASY ? 32 : 40;   // async needs contiguous rows (no pad)
  __shared__ bf16 As[2][128][LDP];
  __shared__ bf16 Bs[2][128][LDP];
  const int tid = threadIdx.x;
  const int lane = tid & 63, wave = tid >> 6;
  const int quad = lane >> 4, l16 = lane & 15;
  const int wr = wave >> 1, wc = wave & 1;
  const int m0 = blockIdx.y * 128, n0 = blockIdx.x * 128;
  const int kbase = blockIdx.z * Kc;
  const bool first = (blockIdx.z == 0);
  const int r0 = tid >> 2, c0 = (tid & 3) * 8;

  const bf16* gA = nullptr; const bf16* gB = nullptr;
  if (ASY) {
    gA = (const bf16*)A + (size_t)(m0 + wave * 16 + (lane >> 2)) * K + kbase + (lane & 3) * 8;
    gB = (const bf16*)Bw + (size_t)(n0 + wave * 16 + (lane >> 2)) * K + kbase + (lane & 3) * 8;
  }

  auto stage = [&](int bi, int kk) {
    if (ASY) {
      const bf16* pA = gA + kk;
      const bf16* pB = gB + kk;
      bf16* la = &As[bi][wave * 16][0];
      bf16* lb = &Bs[bi][wave * 16][0];
      glds16(pA, la);
      glds16(pA + (size_t)64 * K, la + 64 * LDP);
      glds16(pB, lb);
      glds16(pB + (size_t)64 * K, lb + 64 * LDP);
    } else {
      const bool f32a = (EPI == EPI_KV);   // fallback: y fp32, weights fp32
      const size_t kkk = (size_t)(kbase + kk);
      *(bf16x8*)(&As[bi][r0][c0])      = ld8(A,  (size_t)(m0 + r0) * K + kkk + c0, f32a);
      *(bf16x8*)(&As[bi][r0 + 64][c0]) = ld8(A,  (size_t)(m0 + r0 + 64) * K + kkk + c0, f32a);
      *(bf16x8*)(&Bs[bi][r0][c0])      = ld8(Bw, (size_t)(n0 + r0) * K + kkk + c0, true);
      *(bf16x8*)(&Bs[bi][r0 + 64][c0]) = ld8(Bw, (size_t)(n0 + r0 + 64) * K + kkk + c0, true);
    }
  };

  f32x4 acc[4][4];
#pragma unroll
  for (int i = 0; i < 4; ++i)
#pragma unroll
    for (int j = 0; j < 4; ++j)
#pragma unroll
      for (int r = 0; r < 4; ++r) acc[i][j][r] = 0.f;

  stage(0, 0);
  __syncthreads();
  int buf = 0;
  for (int k0 = 0; k0 < Kc; k0 += 32) {
    if (k0 + 32 < Kc) stage(buf ^ 1, k0 + 32);   // prefetch next tile (async)
    bf16x8 af[4], bfv[4];
#pragma unroll
    for (int i = 0; i < 4; ++i) {
      af[i]  = *(const bf16x8*)(&As[buf][wr * 64 + i * 16 + l16][quad * 8]);
      bfv[i] = *(const bf16x8*)(&Bs[buf][wc * 64 + i * 16 + l16][quad * 8]);
    }
#pragma unroll
    for (int mb = 0; mb < 4; ++mb)
#pragma unroll
      for (int nb = 0; nb < 4; ++nb)
        acc[mb][nb] = __builtin_amdgcn_mfma_f32_16x16x32_bf16(af[mb], bfv[nb], acc[mb][nb], 0, 0, 0);
    __syncthreads();   // drains prefetch (vmcnt) + orders buffer reuse
    buf ^= 1;
  }

  // epilogue
#pragma unroll
  for (int mb = 0; mb < 4; ++mb) {
#pragma unroll
    for (int r = 0; r < 4; ++r) {
      const int gm = m0 + wr * 64 + mb * 16 + quad * 4 + r;
#pragma unroll
      for (int nb = 0; nb < 4; ++nb) {
        const int gn = n0 + wc * 64 + nb * 16 + l16;
        float v = acc[mb][nb][r];
        if (EPI == EPI_QKV) {
          if (gm < MACT) {
            unsigned b = (unsigned)gm / 1025u;
            unsigned t = (unsigned)gm - b * 1025u;
            int sec = gn >> 10, e = gn & 1023;
            int h = e >> 6, d = e & 63;
            if (sec == 0)
              out0[((size_t)(b * NHEAD + h) * NQTOK + t) * HD + d] =
                  (bf16)((v + bias0[e]) * QSCALE);
            else if (sec == 1)
              out1[((size_t)(b * NHEAD + h) * NQTOK + t) * HD + d] = (bf16)v;
            else   // V transposed: row = d, col = token
              out2[((size_t)(b * NHEAD + h) * HD + d) * VTS + t] =
                  (bf16)(v + bias1[e]);
          }
        } else if (EPI == EPI_KV) {
          unsigned b = (unsigned)gm >> 10;
          unsigned t = (unsigned)gm & 1023u;
          int sec = gn >> 10, e = gn & 1023;
          int h = e >> 6, d = e & 63;
          if (sec == 0)
            out0[((size_t)(b * NHEAD + h) * NKTOK + t) * HD + d] = (bf16)v;
          else   // V transposed, stride NKTOK (1024, aligned)
            out1[((size_t)(b * NHEAD + h) * HD + d) * NKTOK + t] =
                (bf16)(v + bias1[e]);
        } else if (EPI == EPI_Q) {
          // single K-chunk (z=1): plain store, no atomics, no memset needed
          if (gm < MACT) {
            unsigned b = (unsigned)gm / 1025u;
            unsigned t = (unsigned)gm - b * 1025u;
            int h = gn >> 6, d = gn & 63;
            outf[((size_t)(b * NHEAD + h) * NQTOK + t) * HD + d] =
                (v + bias0[gn]) * QSCALE;
          }
        } else if (EPI == EPI_RES) {
          // single K-chunk (z=1): single writer -> plain RMW, no atomics
          if (gm < MACT) {
            size_t o = (size_t)gm * EDIM + gn;
            xf[o] += gamma[gn] * (v + bias0[gn]);
          }
        } else if (EPI == EPI_GELU) {
          float z = v + bias0[gn];
          float ge = 0.5f * z * (1.0f + erff(z * 0.70710678118f));
          out0[(size_t)gm * FDIM + gn] = (bf16)ge;
        } else if (EPI == EPI_PART) {
          // split-K=2 partials: z=0 -> xf (scratch p0), z=1 -> outf. Plain stores.
          if (gm < MACT) {
            float* dst = first ? xf : outf;
            dst[(size_t)gm * EDIM + gn] = v;
          }
        } else { // EPI_FINAL: fallback path only (d_out f32, zeroed before launch)
          if (gm < MACT) {
            size_t o = (size_t)gm * EDIM + gn;
            float add = gamma[gn] * (v + (first ? bias0[gn] : 0.f));
            if (first) add += xf[o];
            atomicAdd(&outf[o], add);
          }
        }
      }
    }
  }
}

// ---------------- Flash attention (self: causal+rpb, cross: rpb) --------
// grid (17, H, B), block 256 = 4 waves; 64-query tile, 64-key chunks.
// SWAPPED QK^T: S^T = mfma(K,Q) so each lane owns a full softmax row.
// rpb index is affine in the chunk index: idx = ib[kb][r] - 126*c (hoisted);
// causal mask / clamp only in the diagonal chunk; CLS fixups under uniform
// guards. s_setprio(1) around both MFMA clusters (T5).
template<bool CROSS>
__global__ __launch_bounds__(256) void attn_kernel(
    const void* __restrict__ Q, const bf16* __restrict__ Kg,
    const bf16* __restrict__ Vg, const float* __restrict__ rpb,
    bf16* __restrict__ out)
{
  const int NK  = CROSS ? NKTOK : NQTOK;
  const int NRD = CROSS ? 3970 : 3972;
  const int VS  = CROSS ? NKTOK : VTS;     // V^T row stride
  const int qt  = CROSS ? blockIdx.x : (16 - blockIdx.x);  // heavy blocks first
  const int h = blockIdx.y, b = blockIdx.z;
  const int tid = threadIdx.x;
  const int lane = tid & 63, wave = tid >> 6;
  const int quad = lane >> 4, l16 = lane & 15;

  __shared__ bf16 rpb_s[4096];
  __shared__ bf16 Ks[64][72];
  __shared__ bf16 Vt[64][72];        // V^T tile: [d][key]

  for (int i = tid; i < 4096; i += 256)
    rpb_s[i] = (bf16)((i < NRD) ? rpb[(size_t)i * NHEAD + h] : 0.f);

  const int q0 = qt * 64;
  const int qrow = q0 + wave * 16 + l16;   // this lane's softmax row AND Q frag row
  const size_t qhb = (size_t)(b * NHEAD + h) * NQTOK;
  bf16x8 qf0, qf1;
  if (qrow < NQTOK) {
    if (CROSS) {
      const float* Qf = (const float*)Q + (qhb + qrow) * HD;
#pragma unroll
      for (int j = 0; j < 8; ++j) {
        qf0[j] = (bf16)Qf[quad * 8 + j];
        qf1[j] = (bf16)Qf[32 + quad * 8 + j];
      }
    } else {
      const bf16* Qb = (const bf16*)Q;
      qf0 = *(const bf16x8*)(Qb + (qhb + qrow) * HD + quad * 8);
      qf1 = *(const bf16x8*)(Qb + (qhb + qrow) * HD + 32 + quad * 8);
    }
  } else {
#pragma unroll
    for (int j = 0; j < 8; ++j) { qf0[j] = (bf16)0.f; qf1[j] = (bf16)0.f; }
  }

  // lane-local q code; rpb idx = qcode - kcode, kcode = 126*c + ocode(o)
  const int qg = qrow;
  const int qp = qg - 1;
  const int qcode = (qg > 0) ? ((qp >> 5) * 63 + (qp & 31) + 1984) : 0;

  // hoisted per-element idx bases: o = kb*16 + quad*4 + r
  int ib[4][4];
#pragma unroll
  for (int kb = 0; kb < 4; ++kb)
#pragma unroll
    for (int r = 0; r < 4; ++r) {
      const int o = kb * 16 + quad * 4 + r;
      const int om = CROSS ? o : (o - 1);          // may be -1 (signed ok)
      const int ocode = (om >> 5) * 63 + (om & 31);
      ib[kb][r] = qcode - ocode;
    }
  const bool q0cls = (q0 == 0);       // wg contains the CLS query row

  // lane-local softmax state for row q = qrow (identical across the 4 quads)
  float m_run = -1e30f, l_run = 0.f;
  f32x4 oacc[4];                     // [db]: rows q = quad*4+r, cols d
#pragma unroll
  for (int d = 0; d < 4; ++d)
#pragma unroll
    for (int r = 0; r < 4; ++r) oacc[d][r] = 0.f;

  const size_t kvbK = (size_t)(b * NHEAD + h) * NK;
  const size_t vbase = (size_t)(b * NHEAD + h) * HD;
  const int nch = CROSS ? (NKTOK / 64) : (qt + 1);

  const int rr = tid >> 3;            // 0..31 (+32 with vv)
  const int co = (tid & 7) * 8;

  // bpermute source lanes for the P redistribution (loop-invariant)
  const int srcA = (quad & 1) * 32 + l16;   // quads {0,1} or {2,3} base
  const int srcB = srcA + 16;

  bf16x8 krg[2], vrg[2];
  auto stage_load = [&](int c) {
    const int kc = c * 64;
#pragma unroll
    for (int vv = 0; vv < 2; ++vv) {
      const int row = rr + vv * 32;
      // K: natural layout row=key
      if (!CROSS && kc + row >= NK) {
#pragma unroll
        for (int j = 0; j < 8; ++j) krg[vv][j] = (bf16)0.f;
      } else {
        krg[vv] = *(const bf16x8*)(Kg + (kvbK + kc + row) * HD + co);
      }
      // V^T: row=d, col=key
      if (!CROSS && kc + co >= NK) {
#pragma unroll
        for (int j = 0; j < 8; ++j) vrg[vv][j] = (bf16)0.f;
      } else {
        vrg[vv] = *(const bf16x8*)(Vg + (vbase + row) * VS + kc + co);
      }
    }
  };

  stage_load(0);
  int c126 = 0;
  for (int c = 0; c < nch; ++c) {
    const int kc = c * 64;
    if (c) __syncthreads();
#pragma unroll
    for (int vv = 0; vv < 2; ++vv) {
      const int row = rr + vv * 32;
      *(bf16x8*)(&Ks[row][co]) = krg[vv];
      *(bf16x8*)(&Vt[row][co]) = vrg[vv];
    }
    __syncthreads();
    if (c + 1 < nch) stage_load(c + 1);   // prefetch overlaps compute

    // ---- S^T = K Q^T: MFMA cluster first, bias pass after ----
    f32x4 aacc[4];
    __builtin_amdgcn_s_setprio(1);
#pragma unroll
    for (int kb = 0; kb < 4; ++kb) {
      bf16x8 kf0 = *(const bf16x8*)(&Ks[kb * 16 + l16][quad * 8]);
      bf16x8 kf1 = *(const bf16x8*)(&Ks[kb * 16 + l16][32 + quad * 8]);
      f32x4 a;
#pragma unroll
      for (int r = 0; r < 4; ++r) a[r] = 0.f;
      a = __builtin_amdgcn_mfma_f32_16x16x32_bf16(kf0, qf0, a, 0, 0, 0);
      a = __builtin_amdgcn_mfma_f32_16x16x32_bf16(kf1, qf1, a, 0, 0, 0);
      aacc[kb] = a;
    }
    __builtin_amdgcn_s_setprio(0);

    float sv[4][4];
    const bool lastc = (!CROSS) && (c == nch - 1);
    const bool firstc = (c == 0);
    if (!lastc) {
      // interior chunk: fully valid, idx in-range (mask is cheap insurance)
#pragma unroll
      for (int kb = 0; kb < 4; ++kb)
#pragma unroll
        for (int r = 0; r < 4; ++r) {
          int idx = ib[kb][r] - c126;
          if (q0cls) { if (qg == 0) idx = 3969; }
          if (!CROSS && firstc && kb == 0 && r == 0) {
            if (quad == 0) idx = (qg == 0) ? 3971 : 3970;   // kg==0 column
          }
          idx &= 4095;
          sv[kb][r] = aacc[kb][r] + (float)rpb_s[idx];
        }
    } else {
      // diagonal chunk (self): causal mask + clamp
#pragma unroll
      for (int kb = 0; kb < 4; ++kb)
#pragma unroll
        for (int r = 0; r < 4; ++r) {
          int idx = ib[kb][r] - c126;
          if (q0cls) { if (qg == 0) idx = 3969; }
          if (firstc && kb == 0 && r == 0) {
            if (quad == 0) idx = (qg == 0) ? 3971 : 3970;
          }
          idx &= 4095;
          const int kg = kc + kb * 16 + quad * 4 + r;
          const bool valid = (kg < NK) && (kg <= qg);
          sv[kb][r] = valid ? (aacc[kb][r] + (float)rpb_s[idx]) : -1e30f;
        }
    }
    c126 += 126;

    // ---- online softmax: whole row is lane-local ----
    float mx = sv[0][0];
#pragma unroll
    for (int kb = 0; kb < 4; ++kb)
#pragma unroll
      for (int r = 0; r < 4; ++r) mx = fmaxf(mx, sv[kb][r]);
    mx = fmaxf(mx, __shfl_xor(mx, 16));
    mx = fmaxf(mx, __shfl_xor(mx, 32));

    if (!__all(mx - m_run <= 8.f)) {       // defer-max: rescale rarely
      const float mnew = fmaxf(m_run, mx);
      const float alpha = __expf(m_run - mnew);
      m_run = mnew;
      l_run *= alpha;
      float alr[4];
#pragma unroll
      for (int r = 0; r < 4; ++r) alr[r] = __shfl(alpha, quad * 4 + r);
#pragma unroll
      for (int d = 0; d < 4; ++d)
#pragma unroll
        for (int r = 0; r < 4; ++r) oacc[d][r] *= alr[r];
    }

    float rs = 0.f;
    unsigned pk[4][2];                 // packed bf16 pairs: (r0,r1),(r2,r3)
#pragma unroll
    for (int kb = 0; kb < 4; ++kb) {
      float p0 = __expf(sv[kb][0] - m_run);
      float p1 = __expf(sv[kb][1] - m_run);
      float p2 = __expf(sv[kb][2] - m_run);
      float p3 = __expf(sv[kb][3] - m_run);
      rs += (p0 + p1) + (p2 + p3);
      union { __bf16 h[2]; unsigned u; } w0, w1;
      w0.h[0] = (bf16)p0; w0.h[1] = (bf16)p1;
      w1.h[0] = (bf16)p2; w1.h[1] = (bf16)p3;
      pk[kb][0] = w0.u; pk[kb][1] = w1.u;
    }
    rs += __shfl_xor(rs, 16);
    rs += __shfl_xor(rs, 32);
    l_run += rs;

    // ---- redistribute P -> A-frag via bpermute (no LDS) ----
    union { unsigned u[4]; bf16x8 v; } f0, f1;
#pragma unroll
    for (int p = 0; p < 4; ++p) {
      const int src = (p < 2) ? srcA : srcB;
      unsigned a0 = (unsigned)__shfl((int)pk[0][p & 1], src);
      unsigned a1 = (unsigned)__shfl((int)pk[1][p & 1], src);
      unsigned b0 = (unsigned)__shfl((int)pk[2][p & 1], src);
      unsigned b1 = (unsigned)__shfl((int)pk[3][p & 1], src);
      f0.u[p] = (quad < 2) ? a0 : a1;
      f1.u[p] = (quad < 2) ? b0 : b1;
    }

    // ---- O += P V (Vt fragments are b128) ----
    __builtin_amdgcn_s_setprio(1);
#pragma unroll
    for (int db = 0; db < 4; ++db) {
      bf16x8 vf0 = *(const bf16x8*)(&Vt[db * 16 + l16][quad * 8]);
      bf16x8 vf1 = *(const bf16x8*)(&Vt[db * 16 + l16][32 + quad * 8]);
      oacc[db] = __builtin_amdgcn_mfma_f32_16x16x32_bf16(f0.v, vf0, oacc[db], 0, 0, 0);
      oacc[db] = __builtin_amdgcn_mfma_f32_16x16x32_bf16(f1.v, vf1, oacc[db], 0, 0, 0);
    }
    __builtin_amdgcn_s_setprio(0);
  }

  // ---- write O (oacc rows q = q0 + wave*16 + quad*4 + r) ----
#pragma unroll
  for (int r = 0; r < 4; ++r) {
    const int qo = q0 + wave * 16 + quad * 4 + r;
    if (qo < NQTOK) {
      const float inv = 1.f / __shfl(l_run, quad * 4 + r);
      const size_t row = (size_t)b * NQTOK + qo;
#pragma unroll
      for (int db = 0; db < 4; ++db)
        out[row * EDIM + h * HD + db * 16 + l16] = (bf16)(oacc[db][r] * inv);
    }
  }
}

// ---------------- launch ----------------
extern "C" void kernel_launch(void* const* d_in, const int* in_sizes, int n_in,
                              void* d_out, int out_size, void* d_ws, size_t ws_size,
                              hipStream_t stream) {
  (void)in_sizes; (void)n_in; (void)out_size;
  const float* x        = (const float*)d_in[0];
  const float* y        = (const float*)d_in[1];
  const float* n1g      = (const float*)d_in[2];
  const float* n1b      = (const float*)d_in[3];
  const float* n2g      = (const float*)d_in[4];
  const float* n2b      = (const float*)d_in[5];
  const float* n3g      = (const float*)d_in[6];
  const float* n3b      = (const float*)d_in[7];
  const float* sa_qkv_w = (const float*)d_in[8];
  const float* sa_qb    = (const float*)d_in[9];
  const float* sa_vb    = (const float*)d_in[10];
  const float* sa_rpb   = (const float*)d_in[11];
  const float* sa_pw    = (const float*)d_in[12];
  const float* sa_pb    = (const float*)d_in[13];
  const float* ca_qw    = (const float*)d_in[14];
  const float* ca_kvw   = (const float*)d_in[15];
  const float* ca_qb    = (const float*)d_in[16];
  const float* ca_vb    = (const float*)d_in[17];
  const float* ca_rpb   = (const float*)d_in[18];
  const float* ca_pw    = (const float*)d_in[19];
  const float* ca_pb    = (const float*)d_in[20];
  const float* fc1_w    = (const float*)d_in[21];
  const float* fc1_b    = (const float*)d_in[22];
  const float* fc2_w    = (const float*)d_in[23];
  const float* fc2_b    = (const float*)d_in[24];
  const float* g1       = (const float*)d_in[25];
  const float* g2       = (const float*)d_in[26];
  const float* g3       = (const float*)d_in[27];
  float* outf = (float*)d_out;     // f32 output; also cross-attn Q scratch
  float* qtf  = (float*)d_out;

  // Workspace: xf(16.9M) | hln(8.7M) | h1-union(34.6M) | bf16 pool(41.9M)
  char* w = (char*)d_ws;
  float* xf = (float*)w;  w += (size_t)MP * EDIM * 4;
  bf16* hln = (bf16*)w;   w += (size_t)MP * EDIM * 2;
  char* big = w;          w += (size_t)MP * FDIM * 2;
  const size_t qkv_sz = (size_t)4 * NHEAD * NQTOK * HD * 2;       // 8.40 MB
  bf16* qt = (bf16*)big;
  bf16* kt = (bf16*)(big + qkv_sz);
  bf16* vt = (bf16*)(big + 2 * qkv_sz);   // V^T (8.65M self; union has room)
  bf16* h1 = (bf16*)big;
  bf16* wpool = (bf16*)w; w += 20971520UL * 2;
  const bool asy = ((size_t)(w - (char*)d_ws) <= ws_size);

  bf16* qkvw_b = wpool;
  bf16* pw_b   = qkvw_b + 3145728UL;
  bf16* cqw_b  = pw_b   + 1048576UL;
  bf16* ckvw_b = cqw_b  + 1048576UL;
  bf16* cpw_b  = ckvw_b + 2097152UL;
  bf16* fc1w_b = cpw_b  + 1048576UL;
  bf16* fc2w_b = fc1w_b + 4194304UL;
  bf16* y_b    = fc2w_b + 4194304UL;
  // FC2 split-K partial (z=0): 16.8 MB over the front of wpool. By FFN time
  // only fc2w_b (at +24 MB) is still live; overlapped weights are dead
  // (stream-ordered: EPI_GELU's read of fc1w_b completes before EPI_PART).
  float* part0 = (float*)wpool;

  if (asy) {
    WPtrs wp = {{sa_qkv_w, sa_pw, ca_qw, ca_kvw, ca_pw, fc1_w, fc2_w, y}};
    conv_kernel<<<10240, 256, 0, stream>>>(wp, wpool);
  }
  zero_pads_kernel<<<dim3(((MP - MACT) * EDIM + 255) / 256), 256, 0, stream>>>(hln);

  // --- self-attention block ---
  ln_kernel<true><<<MACT, 256, 0, stream>>>(x, xf, hln, n1g, n1b);
  if (asy) gemm_bt<EPI_QKV, true><<<dim3(24, 33, 1), 256, 0, stream>>>(hln, qkvw_b, 1024, 1024,
      sa_qb, sa_vb, nullptr, nullptr, qt, kt, vt, nullptr);
  else     gemm_bt<EPI_QKV, false><<<dim3(24, 33, 1), 256, 0, stream>>>(hln, sa_qkv_w, 1024, 1024,
      sa_qb, sa_vb, nullptr, nullptr, qt, kt, vt, nullptr);
  attn_kernel<false><<<dim3(17, NHEAD, 4), 256, 0, stream>>>(qt, kt, vt, sa_rpb, hln);
  if (asy) gemm_bt<EPI_RES, true><<<dim3(8, 33, 1), 256, 0, stream>>>(hln, pw_b, 1024, 1024,
      sa_pb, nullptr, g1, xf, nullptr, nullptr, nullptr, nullptr);
  else     gemm_bt<EPI_RES, false><<<dim3(8, 33, 1), 256, 0, stream>>>(hln, sa_pw, 1024, 1024,
      sa_pb, nullptr, g1, xf, nullptr, nullptr, nullptr, nullptr);

  // --- cross-attention block ---
  ln_kernel<false><<<MACT, 256, 0, stream>>>(xf, nullptr, hln, n2g, n2b);
  if (asy) gemm_bt<EPI_Q, true><<<dim3(8, 33, 1), 256, 0, stream>>>(hln, cqw_b, 1024, 1024,
      ca_qb, nullptr, nullptr, nullptr, nullptr, nullptr, nullptr, qtf);
  else     gemm_bt<EPI_Q, false><<<dim3(8, 33, 1), 256, 0, stream>>>(hln, ca_qw, 1024, 1024,
      ca_qb, nullptr, nullptr, nullptr, nullptr, nullptr, nullptr, qtf);
  if (asy) gemm_bt<EPI_KV, true><<<dim3(16, 32, 1), 256, 0, stream>>>(y_b, ckvw_b, 1024, 1024,
      nullptr, ca_vb, nullptr, nullptr, kt, vt, nullptr, nullptr);
  else     gemm_bt<EPI_KV, false><<<dim3(16, 32, 1), 256, 0, stream>>>(y, ca_kvw, 1024, 1024,
      nullptr, ca_vb, nullptr, nullptr, kt, vt, nullptr, nullptr);
  attn_kernel<true><<<dim3(17, NHEAD, 4), 256, 0, stream>>>(qtf, kt, vt, ca_rpb, hln);  // 17 tiles!
  if (asy) gemm_bt<EPI_RES, true><<<dim3(8, 33, 1), 256, 0, stream>>>(hln, cpw_b, 1024, 1024,
      ca_pb, nullptr, g2, xf, nullptr, nullptr, nullptr, nullptr);
  else     gemm_bt<EPI_RES, false><<<dim3(8, 33, 1), 256, 0, stream>>>(hln, ca_pw, 1024, 1024,
      ca_pb, nullptr, g2, xf, nullptr, nullptr, nullptr, nullptr);

  // --- FFN ---
  ln_kernel<false><<<MACT, 256, 0, stream>>>(xf, nullptr, hln, n3g, n3b);
  if (asy) gemm_bt<EPI_GELU, true><<<dim3(32, 33, 1), 256, 0, stream>>>(hln, fc1w_b, 1024, 1024,
      fc1_b, nullptr, nullptr, nullptr, h1, nullptr, nullptr, nullptr);
  else     gemm_bt<EPI_GELU, false><<<dim3(32, 33, 1), 256, 0, stream>>>(hln, fc1_w, 1024, 1024,
      fc1_b, nullptr, nullptr, nullptr, h1, nullptr, nullptr, nullptr);
  if (asy) {
    // split-K=2, plain partial stores (z=0 -> part0, z=1 -> outf), then combine
    gemm_bt<EPI_PART, true><<<dim3(8, 33, 2), 256, 0, stream>>>(h1, fc2w_b, 4096, 2048,
        nullptr, nullptr, nullptr, part0, nullptr, nullptr, nullptr, outf);
    fc2_reduce_kernel<<<dim3(4100), 256, 0, stream>>>(part0, xf, fc2_b, g3, outf);
  } else {
    hipMemsetAsync(outf, 0, (size_t)MACT * EDIM * 4, stream);  // reset for final
    gemm_bt<EPI_FINAL, false><<<dim3(8, 33, 4), 256, 0, stream>>>(h1, fc2_w, 4096, 1024,
        fc2_b, nullptr, g3, xf, nullptr, nullptr, nullptr, outf);
  }
}

// Round 5
// 675.248 us; speedup vs baseline: 1.2240x; 1.0048x over previous
//
#include <hip/hip_runtime.h>
#include <hip/hip_bf16.h>
#include <math.h>

typedef __bf16 bf16;
typedef __bf16 bf16x8 __attribute__((ext_vector_type(8)));
typedef float f32x4 __attribute__((ext_vector_type(4)));

#define MP    4224      // padded token rows (33*128)
#define MACT  4100      // B*N = 4*1025
#define NQTOK 1025
#define NKTOK 1024
#define EDIM  1024
#define FDIM  4096
#define NHEAD 16
#define HD    64
#define QSCALE 0.125f
#define VTS   1056      // self V^T row stride (16B-aligned, > 1025)
#define NROWS 65600     // B*H*NQTOK = 4*16*1025 attention output rows

// ---- async global->LDS, 16B per lane; LDS base must be wave-uniform ----
__device__ __forceinline__ void glds16(const bf16* g, bf16* l) {
  __builtin_amdgcn_global_load_lds(
      (const __attribute__((address_space(1))) void*)g,
      (__attribute__((address_space(3))) void*)l, 16, 0, 0);
}

// scalar / 8-wide fp32->bf16 loads (fallback + conversion paths)
__device__ __forceinline__ bf16x8 ld8(const void* p, size_t i, bool f32) {
  if (f32) {
    const float* q = (const float*)p + i;
    bf16x8 r;
#pragma unroll
    for (int j = 0; j < 8; ++j) r[j] = (bf16)q[j];
    return r;
  }
  return *(const bf16x8*)((const bf16*)p + i);
}

// ---- weight/y fp32 -> bf16 pool conversion (one pass per launch) ----
struct WPtrs { const float* s[8]; };
__global__ __launch_bounds__(256) void conv_kernel(WPtrs wp, bf16* dst) {
  const size_t sz[8] = {3145728UL, 1048576UL, 1048576UL, 2097152UL,
                        1048576UL, 4194304UL, 4194304UL, 4194304UL};
  size_t id = ((size_t)blockIdx.x * 256 + threadIdx.x) * 8;
  size_t off = 0;
#pragma unroll
  for (int i = 0; i < 8; ++i) {
    if (id < off + sz[i]) {
      const float* s = wp.s[i] + (id - off);
      bf16x8 r;
#pragma unroll
      for (int j = 0; j < 8; ++j) r[j] = (bf16)s[j];
      *(bf16x8*)(dst + id) = r;
      return;
    }
    off += sz[i];
  }
}

// ---------------- zero the pad rows of hln ----------------
__global__ void zero_pads_kernel(bf16* hln) {
  int i = blockIdx.x * 256 + threadIdx.x;
  const int n = (MP - MACT) * EDIM;
  if (i < n) hln[(size_t)MACT * EDIM + i] = (bf16)0.0f;
}

// ---------------- LayerNorm (one block per token) ----------------
template<bool FIRST>
__global__ __launch_bounds__(256) void ln_kernel(const float* __restrict__ src,
    float* __restrict__ xf, bf16* __restrict__ out,
    const float* __restrict__ g, const float* __restrict__ bta) {
  const int row = blockIdx.x;
  const int tid = threadIdx.x;
  float v[4];
#pragma unroll
  for (int i = 0; i < 4; ++i) {
    v[i] = src[(size_t)row * EDIM + tid + i * 256];
    if (FIRST) xf[(size_t)row * EDIM + tid + i * 256] = v[i];
  }
  float s = 0.f, sq = 0.f;
#pragma unroll
  for (int i = 0; i < 4; ++i) { s += v[i]; sq += v[i] * v[i]; }
#pragma unroll
  for (int m = 32; m >= 1; m >>= 1) {
    s += __shfl_xor(s, m);
    sq += __shfl_xor(sq, m);
  }
  __shared__ float ss[4], ssq[4];
  const int wave = tid >> 6;
  if ((tid & 63) == 0) { ss[wave] = s; ssq[wave] = sq; }
  __syncthreads();
  s = ss[0] + ss[1] + ss[2] + ss[3];
  sq = ssq[0] + ssq[1] + ssq[2] + ssq[3];
  const float mean = s * (1.f / EDIM);
  const float var = sq * (1.f / EDIM) - mean * mean;
  const float rstd = rsqrtf(var + 1e-5f);
#pragma unroll
  for (int i = 0; i < 4; ++i) {
    int e = tid + i * 256;
    out[(size_t)row * EDIM + e] = (bf16)((v[i] - mean) * rstd * g[e] + bta[e]);
  }
}

// ---------------- FC2 combine: outf = xf + g3*(p0 + p1 + bias) ------------
__global__ __launch_bounds__(256) void fc2_reduce_kernel(
    const float* __restrict__ p0, const float* __restrict__ xf,
    const float* __restrict__ bias, const float* __restrict__ gamma,
    float* __restrict__ outf) {
  size_t i = ((size_t)blockIdx.x * 256 + threadIdx.x) * 4;
  if (i >= (size_t)MACT * EDIM) return;
  f32x4 a = *(const f32x4*)(p0 + i);
  f32x4 b = *(const f32x4*)(outf + i);
  f32x4 x = *(const f32x4*)(xf + i);
  const int gn = (int)(i & (EDIM - 1));
  f32x4 r;
#pragma unroll
  for (int j = 0; j < 4; ++j)
    r[j] = x[j] + gamma[gn + j] * (a[j] + b[j] + bias[gn + j]);
  *(f32x4*)(outf + i) = r;
}

// ---------------- attn split combine: out = (w0*O0 + w1*O1) --------------
// partials are self-normalized; weights w_s = exp(m_s-M)*l_s renormalized.
__global__ __launch_bounds__(256) void attn_combine_kernel(
    const bf16* __restrict__ opart, const float* __restrict__ mlbuf,
    bf16* __restrict__ out) {
  const int tid = threadIdx.x;
  const int row = blockIdx.x * 32 + (tid >> 3);
  const int d0 = (tid & 7) * 8;
  if (row >= NROWS) return;
  const float m0 = mlbuf[(size_t)row * 2],           l0 = mlbuf[(size_t)row * 2 + 1];
  const float m1 = mlbuf[((size_t)NROWS + row) * 2], l1 = mlbuf[((size_t)NROWS + row) * 2 + 1];
  const float M = fmaxf(m0, m1);
  float w0 = __expf(m0 - M) * l0;
  float w1 = __expf(m1 - M) * l1;
  const float den = w0 + w1;
  const float sc = (den > 0.f) ? 1.f / den : 0.f;
  w0 *= sc; w1 *= sc;
  const size_t OPSZ = (size_t)NROWS * HD;
  bf16x8 a = *(const bf16x8*)(opart + (size_t)row * HD + d0);
  bf16x8 c = *(const bf16x8*)(opart + OPSZ + (size_t)row * HD + d0);
  const int b = row / (NHEAD * NQTOK);
  const int rem = row - b * (NHEAD * NQTOK);
  const int h = rem / NQTOK;
  const int q = rem - h * NQTOK;
  bf16x8 o;
#pragma unroll
  for (int j = 0; j < 8; ++j)
    o[j] = (bf16)(w0 * (float)a[j] + w1 * (float)c[j]);
  *(bf16x8*)(out + ((size_t)b * NQTOK + q) * EDIM + h * HD + d0) = o;
}

// ---------------- GEMM: C[m,n] = sum_k A[m,k]*B[n,k], fused epilogues ----
// Double-buffered LDS, 2-phase pattern: stage(next) issued BEFORE compute(cur),
// ONE barrier per K-step. V outputs written TRANSPOSED: V^T[(b,h,d), key].
enum { EPI_QKV = 0, EPI_KV = 1, EPI_Q = 2, EPI_RES = 3, EPI_GELU = 4,
       EPI_FINAL = 5, EPI_PART = 6 };

template<int EPI, bool ASY>
__global__ __launch_bounds__(256) void gemm_bt(
    const void* __restrict__ A, const void* __restrict__ Bw,
    int K, int Kc,
    const float* __restrict__ bias0, const float* __restrict__ bias1,
    const float* __restrict__ gamma, float* __restrict__ xf,
    bf16* __restrict__ out0, bf16* __restrict__ out1, bf16* __restrict__ out2,
    float* __restrict__ outf)
{
  constexpr int LDP = ASY ? 32 : 40;   // async needs contiguous rows (no pad)
  __shared__ bf16 As[2][128][LDP];
  __shared__ bf16 Bs[2][128][LDP];
  const int tid = threadIdx.x;
  const int lane = tid & 63, wave = tid >> 6;
  const int quad = lane >> 4, l16 = lane & 15;
  const int wr = wave >> 1, wc = wave & 1;
  const int m0 = blockIdx.y * 128, n0 = blockIdx.x * 128;
  const int kbase = blockIdx.z * Kc;
  const bool first = (blockIdx.z == 0);
  const int r0 = tid >> 2, c0 = (tid & 3) * 8;

  const bf16* gA = nullptr; const bf16* gB = nullptr;
  if (ASY) {
    gA = (const bf16*)A + (size_t)(m0 + wave * 16 + (lane >> 2)) * K + kbase + (lane & 3) * 8;
    gB = (const bf16*)Bw + (size_t)(n0 + wave * 16 + (lane >> 2)) * K + kbase + (lane & 3) * 8;
  }

  auto stage = [&](int bi, int kk) {
    if (ASY) {
      const bf16* pA = gA + kk;
      const bf16* pB = gB + kk;
      bf16* la = &As[bi][wave * 16][0];
      bf16* lb = &Bs[bi][wave * 16][0];
      glds16(pA, la);
      glds16(pA + (size_t)64 * K, la + 64 * LDP);
      glds16(pB, lb);
      glds16(pB + (size_t)64 * K, lb + 64 * LDP);
    } else {
      const bool f32a = (EPI == EPI_KV);   // fallback: y fp32, weights fp32
      const size_t kkk = (size_t)(kbase + kk);
      *(bf16x8*)(&As[bi][r0][c0])      = ld8(A,  (size_t)(m0 + r0) * K + kkk + c0, f32a);
      *(bf16x8*)(&As[bi][r0 + 64][c0]) = ld8(A,  (size_t)(m0 + r0 + 64) * K + kkk + c0, f32a);
      *(bf16x8*)(&Bs[bi][r0][c0])      = ld8(Bw, (size_t)(n0 + r0) * K + kkk + c0, true);
      *(bf16x8*)(&Bs[bi][r0 + 64][c0]) = ld8(Bw, (size_t)(n0 + r0 + 64) * K + kkk + c0, true);
    }
  };

  f32x4 acc[4][4];
#pragma unroll
  for (int i = 0; i < 4; ++i)
#pragma unroll
    for (int j = 0; j < 4; ++j)
#pragma unroll
      for (int r = 0; r < 4; ++r) acc[i][j][r] = 0.f;

  stage(0, 0);
  __syncthreads();
  int buf = 0;
  for (int k0 = 0; k0 < Kc; k0 += 32) {
    if (k0 + 32 < Kc) stage(buf ^ 1, k0 + 32);   // prefetch next tile (async)
    bf16x8 af[4], bfv[4];
#pragma unroll
    for (int i = 0; i < 4; ++i) {
      af[i]  = *(const bf16x8*)(&As[buf][wr * 64 + i * 16 + l16][quad * 8]);
      bfv[i] = *(const bf16x8*)(&Bs[buf][wc * 64 + i * 16 + l16][quad * 8]);
    }
#pragma unroll
    for (int mb = 0; mb < 4; ++mb)
#pragma unroll
      for (int nb = 0; nb < 4; ++nb)
        acc[mb][nb] = __builtin_amdgcn_mfma_f32_16x16x32_bf16(af[mb], bfv[nb], acc[mb][nb], 0, 0, 0);
    __syncthreads();   // drains prefetch (vmcnt) + orders buffer reuse
    buf ^= 1;
  }

  // epilogue
#pragma unroll
  for (int mb = 0; mb < 4; ++mb) {
#pragma unroll
    for (int r = 0; r < 4; ++r) {
      const int gm = m0 + wr * 64 + mb * 16 + quad * 4 + r;
#pragma unroll
      for (int nb = 0; nb < 4; ++nb) {
        const int gn = n0 + wc * 64 + nb * 16 + l16;
        float v = acc[mb][nb][r];
        if (EPI == EPI_QKV) {
          if (gm < MACT) {
            unsigned b = (unsigned)gm / 1025u;
            unsigned t = (unsigned)gm - b * 1025u;
            int sec = gn >> 10, e = gn & 1023;
            int h = e >> 6, d = e & 63;
            if (sec == 0)
              out0[((size_t)(b * NHEAD + h) * NQTOK + t) * HD + d] =
                  (bf16)((v + bias0[e]) * QSCALE);
            else if (sec == 1)
              out1[((size_t)(b * NHEAD + h) * NQTOK + t) * HD + d] = (bf16)v;
            else   // V transposed: row = d, col = token
              out2[((size_t)(b * NHEAD + h) * HD + d) * VTS + t] =
                  (bf16)(v + bias1[e]);
          }
        } else if (EPI == EPI_KV) {
          unsigned b = (unsigned)gm >> 10;
          unsigned t = (unsigned)gm & 1023u;
          int sec = gn >> 10, e = gn & 1023;
          int h = e >> 6, d = e & 63;
          if (sec == 0)
            out0[((size_t)(b * NHEAD + h) * NKTOK + t) * HD + d] = (bf16)v;
          else   // V transposed, stride NKTOK (1024, aligned)
            out1[((size_t)(b * NHEAD + h) * HD + d) * NKTOK + t] =
                (bf16)(v + bias1[e]);
        } else if (EPI == EPI_Q) {
          // cross Q -> bf16 (b,h,t,d); frees d_out for attn partials
          if (gm < MACT) {
            unsigned b = (unsigned)gm / 1025u;
            unsigned t = (unsigned)gm - b * 1025u;
            int h = gn >> 6, d = gn & 63;
            out0[((size_t)(b * NHEAD + h) * NQTOK + t) * HD + d] =
                (bf16)((v + bias0[gn]) * QSCALE);
          }
        } else if (EPI == EPI_RES) {
          // single K-chunk (z=1): single writer -> plain RMW, no atomics
          if (gm < MACT) {
            size_t o = (size_t)gm * EDIM + gn;
            xf[o] += gamma[gn] * (v + bias0[gn]);
          }
        } else if (EPI == EPI_GELU) {
          float z = v + bias0[gn];
          float ge = 0.5f * z * (1.0f + erff(z * 0.70710678118f));
          out0[(size_t)gm * FDIM + gn] = (bf16)ge;
        } else if (EPI == EPI_PART) {
          // split-K=2 partials: z=0 -> xf (scratch p0), z=1 -> outf. Plain stores.
          if (gm < MACT) {
            float* dst = first ? xf : outf;
            dst[(size_t)gm * EDIM + gn] = v;
          }
        } else { // EPI_FINAL: fallback path only (d_out f32, zeroed before launch)
          if (gm < MACT) {
            size_t o = (size_t)gm * EDIM + gn;
            float add = gamma[gn] * (v + (first ? bias0[gn] : 0.f));
            if (first) add += xf[o];
            atomicAdd(&outf[o], add);
          }
        }
      }
    }
  }
}

// ---------------- Flash attention (self: causal+rpb, cross: rpb) --------
// grid (17, H, B*2): blockIdx.z = b + 4*s; split s processes chunks c==s (mod 2)
// with independent online (m,l,O). Partial O (self-normalized, bf16) + (m,l)
// go to scratch; attn_combine merges. SWAPPED QK^T: lane owns a softmax row.
// rpb idx affine in chunk: idx = ib[kb][r] - 126*c. setprio around MFMA (T5).
template<bool CROSS>
__global__ __launch_bounds__(256) void attn_kernel(
    const bf16* __restrict__ Qg, const bf16* __restrict__ Kg,
    const bf16* __restrict__ Vg, const float* __restrict__ rpb,
    bf16* __restrict__ opart, float* __restrict__ mlbuf)
{
  const int NK  = CROSS ? NKTOK : NQTOK;
  const int NRD = CROSS ? 3970 : 3972;
  const int VS  = CROSS ? NKTOK : VTS;     // V^T row stride
  const int qt  = CROSS ? blockIdx.x : (16 - blockIdx.x);  // heavy blocks first
  const int h = blockIdx.y;
  const int b = blockIdx.z & 3, s = blockIdx.z >> 2;
  const int tid = threadIdx.x;
  const int lane = tid & 63, wave = tid >> 6;
  const int quad = lane >> 4, l16 = lane & 15;

  __shared__ bf16 rpb_s[4096];
  __shared__ bf16 Ks[64][72];
  __shared__ bf16 Vt[64][72];        // V^T tile: [d][key]

  for (int i = tid; i < 4096; i += 256)
    rpb_s[i] = (bf16)((i < NRD) ? rpb[(size_t)i * NHEAD + h] : 0.f);

  const int q0 = qt * 64;
  const int qrow = q0 + wave * 16 + l16;   // this lane's softmax row AND Q frag row
  const size_t qhb = (size_t)(b * NHEAD + h) * NQTOK;
  bf16x8 qf0, qf1;
  if (qrow < NQTOK) {
    qf0 = *(const bf16x8*)(Qg + (qhb + qrow) * HD + quad * 8);
    qf1 = *(const bf16x8*)(Qg + (qhb + qrow) * HD + 32 + quad * 8);
  } else {
#pragma unroll
    for (int j = 0; j < 8; ++j) { qf0[j] = (bf16)0.f; qf1[j] = (bf16)0.f; }
  }

  // lane-local q code; rpb idx = qcode - kcode, kcode = 126*c + ocode(o)
  const int qg = qrow;
  const int qp = qg - 1;
  const int qcode = (qg > 0) ? ((qp >> 5) * 63 + (qp & 31) + 1984) : 0;

  // hoisted per-element idx bases: o = kb*16 + quad*4 + r
  int ib[4][4];
#pragma unroll
  for (int kb = 0; kb < 4; ++kb)
#pragma unroll
    for (int r = 0; r < 4; ++r) {
      const int o = kb * 16 + quad * 4 + r;
      const int om = CROSS ? o : (o - 1);          // may be -1 (signed ok)
      const int ocode = (om >> 5) * 63 + (om & 31);
      ib[kb][r] = qcode - ocode;
    }
  const bool q0cls = (q0 == 0);       // wg contains the CLS query row

  // lane-local softmax state for row q = qrow (identical across the 4 quads)
  float m_run = -1e30f, l_run = 0.f;
  f32x4 oacc[4];                     // [db]: rows q = quad*4+r, cols d
#pragma unroll
  for (int d = 0; d < 4; ++d)
#pragma unroll
    for (int r = 0; r < 4; ++r) oacc[d][r] = 0.f;

  const size_t kvbK = (size_t)(b * NHEAD + h) * NK;
  const size_t vbase = (size_t)(b * NHEAD + h) * HD;
  const int nch = CROSS ? (NKTOK / 64) : (qt + 1);

  const int rr = tid >> 3;            // 0..31 (+32 with vv)
  const int co = (tid & 7) * 8;

  // bpermute source lanes for the P redistribution (loop-invariant)
  const int srcA = (quad & 1) * 32 + l16;   // quads {0,1} or {2,3} base
  const int srcB = srcA + 16;

  bf16x8 krg[2], vrg[2];
  auto stage_load = [&](int c) {
    const int kc = c * 64;
#pragma unroll
    for (int vv = 0; vv < 2; ++vv) {
      const int row = rr + vv * 32;
      // K: natural layout row=key
      if (!CROSS && kc + row >= NK) {
#pragma unroll
        for (int j = 0; j < 8; ++j) krg[vv][j] = (bf16)0.f;
      } else {
        krg[vv] = *(const bf16x8*)(Kg + (kvbK + kc + row) * HD + co);
      }
      // V^T: row=d, col=key
      if (!CROSS && kc + co >= NK) {
#pragma unroll
        for (int j = 0; j < 8; ++j) vrg[vv][j] = (bf16)0.f;
      } else {
        vrg[vv] = *(const bf16x8*)(Vg + (vbase + row) * VS + kc + co);
      }
    }
  };

  if (s < nch) stage_load(s);
  int c126 = s * 126;
  for (int c = s; c < nch; c += 2) {
    const int kc = c * 64;
    if (c != s) __syncthreads();
#pragma unroll
    for (int vv = 0; vv < 2; ++vv) {
      const int row = rr + vv * 32;
      *(bf16x8*)(&Ks[row][co]) = krg[vv];
      *(bf16x8*)(&Vt[row][co]) = vrg[vv];
    }
    __syncthreads();
    if (c + 2 < nch) stage_load(c + 2);   // prefetch overlaps compute

    // ---- S^T = K Q^T: MFMA cluster first, bias pass after ----
    f32x4 aacc[4];
    __builtin_amdgcn_s_setprio(1);
#pragma unroll
    for (int kb = 0; kb < 4; ++kb) {
      bf16x8 kf0 = *(const bf16x8*)(&Ks[kb * 16 + l16][quad * 8]);
      bf16x8 kf1 = *(const bf16x8*)(&Ks[kb * 16 + l16][32 + quad * 8]);
      f32x4 a;
#pragma unroll
      for (int r = 0; r < 4; ++r) a[r] = 0.f;
      a = __builtin_amdgcn_mfma_f32_16x16x32_bf16(kf0, qf0, a, 0, 0, 0);
      a = __builtin_amdgcn_mfma_f32_16x16x32_bf16(kf1, qf1, a, 0, 0, 0);
      aacc[kb] = a;
    }
    __builtin_amdgcn_s_setprio(0);

    float sv[4][4];
    const bool lastc = (!CROSS) && (c == nch - 1);
    const bool firstc = (c == 0);
    if (!lastc) {
      // interior chunk: fully valid, idx in-range (mask is cheap insurance)
#pragma unroll
      for (int kb = 0; kb < 4; ++kb)
#pragma unroll
        for (int r = 0; r < 4; ++r) {
          int idx = ib[kb][r] - c126;
          if (q0cls) { if (qg == 0) idx = 3969; }
          if (!CROSS && firstc && kb == 0 && r == 0) {
            if (quad == 0) idx = (qg == 0) ? 3971 : 3970;   // kg==0 column
          }
          idx &= 4095;
          sv[kb][r] = aacc[kb][r] + (float)rpb_s[idx];
        }
    } else {
      // diagonal chunk (self): causal mask + clamp
#pragma unroll
      for (int kb = 0; kb < 4; ++kb)
#pragma unroll
        for (int r = 0; r < 4; ++r) {
          int idx = ib[kb][r] - c126;
          if (q0cls) { if (qg == 0) idx = 3969; }
          if (firstc && kb == 0 && r == 0) {
            if (quad == 0) idx = (qg == 0) ? 3971 : 3970;
          }
          idx &= 4095;
          const int kg = kc + kb * 16 + quad * 4 + r;
          const bool valid = (kg < NK) && (kg <= qg);
          sv[kb][r] = valid ? (aacc[kb][r] + (float)rpb_s[idx]) : -1e30f;
        }
    }
    c126 += 252;

    // ---- online softmax: whole row is lane-local ----
    float mx = sv[0][0];
#pragma unroll
    for (int kb = 0; kb < 4; ++kb)
#pragma unroll
      for (int r = 0; r < 4; ++r) mx = fmaxf(mx, sv[kb][r]);
    mx = fmaxf(mx, __shfl_xor(mx, 16));
    mx = fmaxf(mx, __shfl_xor(mx, 32));

    if (!__all(mx - m_run <= 8.f)) {       // defer-max: rescale rarely
      const float mnew = fmaxf(m_run, mx);
      const float alpha = __expf(m_run - mnew);
      m_run = mnew;
      l_run *= alpha;
      float alr[4];
#pragma unroll
      for (int r = 0; r < 4; ++r) alr[r] = __shfl(alpha, quad * 4 + r);
#pragma unroll
      for (int d = 0; d < 4; ++d)
#pragma unroll
        for (int r = 0; r < 4; ++r) oacc[d][r] *= alr[r];
    }

    float rs = 0.f;
    unsigned pk[4][2];                 // packed bf16 pairs: (r0,r1),(r2,r3)
#pragma unroll
    for (int kb = 0; kb < 4; ++kb) {
      float p0 = __expf(sv[kb][0] - m_run);
      float p1 = __expf(sv[kb][1] - m_run);
      float p2 = __expf(sv[kb][2] - m_run);
      float p3 = __expf(sv[kb][3] - m_run);
      rs += (p0 + p1) + (p2 + p3);
      union { __bf16 h[2]; unsigned u; } w0, w1;
      w0.h[0] = (bf16)p0; w0.h[1] = (bf16)p1;
      w1.h[0] = (bf16)p2; w1.h[1] = (bf16)p3;
      pk[kb][0] = w0.u; pk[kb][1] = w1.u;
    }
    rs += __shfl_xor(rs, 16);
    rs += __shfl_xor(rs, 32);
    l_run += rs;

    // ---- redistribute P -> A-frag via bpermute (no LDS) ----
    union { unsigned u[4]; bf16x8 v; } f0, f1;
#pragma unroll
    for (int p = 0; p < 4; ++p) {
      const int src = (p < 2) ? srcA : srcB;
      unsigned a0 = (unsigned)__shfl((int)pk[0][p & 1], src);
      unsigned a1 = (unsigned)__shfl((int)pk[1][p & 1], src);
      unsigned b0 = (unsigned)__shfl((int)pk[2][p & 1], src);
      unsigned b1 = (unsigned)__shfl((int)pk[3][p & 1], src);
      f0.u[p] = (quad < 2) ? a0 : a1;
      f1.u[p] = (quad < 2) ? b0 : b1;
    }

    // ---- O += P V (Vt fragments are b128) ----
    __builtin_amdgcn_s_setprio(1);
#pragma unroll
    for (int db = 0; db < 4; ++db) {
      bf16x8 vf0 = *(const bf16x8*)(&Vt[db * 16 + l16][quad * 8]);
      bf16x8 vf1 = *(const bf16x8*)(&Vt[db * 16 + l16][32 + quad * 8]);
      oacc[db] = __builtin_amdgcn_mfma_f32_16x16x32_bf16(f0.v, vf0, oacc[db], 0, 0, 0);
      oacc[db] = __builtin_amdgcn_mfma_f32_16x16x32_bf16(f1.v, vf1, oacc[db], 0, 0, 0);
    }
    __builtin_amdgcn_s_setprio(0);
  }

  // ---- write partial O (self-normalized) + (m,l) ----
  const size_t OPSZ = (size_t)NROWS * HD;
#pragma unroll
  for (int r = 0; r < 4; ++r) {
    const int qo = q0 + wave * 16 + quad * 4 + r;
    if (qo < NQTOK) {
      const float lr = __shfl(l_run, quad * 4 + r);
      const float inv = (lr > 0.f) ? 1.f / lr : 0.f;
      const size_t orow = (size_t)(b * NHEAD + h) * NQTOK + qo;
#pragma unroll
      for (int db = 0; db < 4; ++db)
        opart[(size_t)s * OPSZ + orow * HD + db * 16 + l16] =
            (bf16)(oacc[db][r] * inv);
    }
  }
  if (quad == 0 && qrow < NQTOK) {
    const size_t orow = (size_t)(b * NHEAD + h) * NQTOK + qrow;
    mlbuf[((size_t)s * NROWS + orow) * 2 + 0] = m_run;
    mlbuf[((size_t)s * NROWS + orow) * 2 + 1] = l_run;
  }
}

// ---------------- launch ----------------
extern "C" void kernel_launch(void* const* d_in, const int* in_sizes, int n_in,
                              void* d_out, int out_size, void* d_ws, size_t ws_size,
                              hipStream_t stream) {
  (void)in_sizes; (void)n_in; (void)out_size;
  const float* x        = (const float*)d_in[0];
  const float* y        = (const float*)d_in[1];
  const float* n1g      = (const float*)d_in[2];
  const float* n1b      = (const float*)d_in[3];
  const float* n2g      = (const float*)d_in[4];
  const float* n2b      = (const float*)d_in[5];
  const float* n3g      = (const float*)d_in[6];
  const float* n3b      = (const float*)d_in[7];
  const float* sa_qkv_w = (const float*)d_in[8];
  const float* sa_qb    = (const float*)d_in[9];
  const float* sa_vb    = (const float*)d_in[10];
  const float* sa_rpb   = (const float*)d_in[11];
  const float* sa_pw    = (const float*)d_in[12];
  const float* sa_pb    = (const float*)d_in[13];
  const float* ca_qw    = (const float*)d_in[14];
  const float* ca_kvw   = (const float*)d_in[15];
  const float* ca_qb    = (const float*)d_in[16];
  const float* ca_vb    = (const float*)d_in[17];
  const float* ca_rpb   = (const float*)d_in[18];
  const float* ca_pw    = (const float*)d_in[19];
  const float* ca_pb    = (const float*)d_in[20];
  const float* fc1_w    = (const float*)d_in[21];
  const float* fc1_b    = (const float*)d_in[22];
  const float* fc2_w    = (const float*)d_in[23];
  const float* fc2_b    = (const float*)d_in[24];
  const float* g1       = (const float*)d_in[25];
  const float* g2       = (const float*)d_in[26];
  const float* g3       = (const float*)d_in[27];
  float* outf = (float*)d_out;      // f32 output; also attn partial-O scratch
  bf16* opart = (bf16*)d_out;       // 2 x 8.4MB bf16 partials fit exactly

  // Workspace: xf(16.9M) | hln(8.7M) | h1-union(34.6M) | bf16 pool(41.9M)
  char* w = (char*)d_ws;
  float* xf = (float*)w;  w += (size_t)MP * EDIM * 4;
  bf16* hln = (bf16*)w;   w += (size_t)MP * EDIM * 2;
  char* big = w;          w += (size_t)MP * FDIM * 2;
  const size_t qkv_sz = (size_t)4 * NHEAD * NQTOK * HD * 2;       // 8.40 MB
  bf16* qt = (bf16*)big;
  bf16* kt = (bf16*)(big + qkv_sz);
  bf16* vt = (bf16*)(big + 2 * qkv_sz);   // V^T (8.65M self; union has room)
  bf16* h1 = (bf16*)big;
  // attn (m,l) scratch: 1.05MB in the dead tail of big (past vt end 25.45MB;
  // big is only fully live as h1 during FFN, after both combines are done)
  float* mlf = (float*)(big + 26214400UL);
  bf16* wpool = (bf16*)w; w += 20971520UL * 2;
  const bool asy = ((size_t)(w - (char*)d_ws) <= ws_size);

  bf16* qkvw_b = wpool;
  bf16* pw_b   = qkvw_b + 3145728UL;
  bf16* cqw_b  = pw_b   + 1048576UL;
  bf16* ckvw_b = cqw_b  + 1048576UL;
  bf16* cpw_b  = ckvw_b + 2097152UL;
  bf16* fc1w_b = cpw_b  + 1048576UL;
  bf16* fc2w_b = fc1w_b + 4194304UL;
  bf16* y_b    = fc2w_b + 4194304UL;
  // FC2 split-K partial (z=0): 16.8 MB over the front of wpool. By FFN time
  // only fc2w_b (at +24 MB) is still live; overlapped weights are dead
  // (stream-ordered: EPI_GELU's read of fc1w_b completes before EPI_PART).
  float* part0 = (float*)wpool;

  if (asy) {
    WPtrs wp = {{sa_qkv_w, sa_pw, ca_qw, ca_kvw, ca_pw, fc1_w, fc2_w, y}};
    conv_kernel<<<10240, 256, 0, stream>>>(wp, wpool);
  }
  zero_pads_kernel<<<dim3(((MP - MACT) * EDIM + 255) / 256), 256, 0, stream>>>(hln);

  // --- self-attention block ---
  ln_kernel<true><<<MACT, 256, 0, stream>>>(x, xf, hln, n1g, n1b);
  if (asy) gemm_bt<EPI_QKV, true><<<dim3(24, 33, 1), 256, 0, stream>>>(hln, qkvw_b, 1024, 1024,
      sa_qb, sa_vb, nullptr, nullptr, qt, kt, vt, nullptr);
  else     gemm_bt<EPI_QKV, false><<<dim3(24, 33, 1), 256, 0, stream>>>(hln, sa_qkv_w, 1024, 1024,
      sa_qb, sa_vb, nullptr, nullptr, qt, kt, vt, nullptr);
  attn_kernel<false><<<dim3(17, NHEAD, 8), 256, 0, stream>>>(qt, kt, vt, sa_rpb, opart, mlf);
  attn_combine_kernel<<<dim3(NROWS / 32), 256, 0, stream>>>(opart, mlf, hln);
  if (asy) gemm_bt<EPI_RES, true><<<dim3(8, 33, 1), 256, 0, stream>>>(hln, pw_b, 1024, 1024,
      sa_pb, nullptr, g1, xf, nullptr, nullptr, nullptr, nullptr);
  else     gemm_bt<EPI_RES, false><<<dim3(8, 33, 1), 256, 0, stream>>>(hln, sa_pw, 1024, 1024,
      sa_pb, nullptr, g1, xf, nullptr, nullptr, nullptr, nullptr);

  // --- cross-attention block ---
  ln_kernel<false><<<MACT, 256, 0, stream>>>(xf, nullptr, hln, n2g, n2b);
  if (asy) gemm_bt<EPI_Q, true><<<dim3(8, 33, 1), 256, 0, stream>>>(hln, cqw_b, 1024, 1024,
      ca_qb, nullptr, nullptr, nullptr, qt, nullptr, nullptr, nullptr);
  else     gemm_bt<EPI_Q, false><<<dim3(8, 33, 1), 256, 0, stream>>>(hln, ca_qw, 1024, 1024,
      ca_qb, nullptr, nullptr, nullptr, qt, nullptr, nullptr, nullptr);
  if (asy) gemm_bt<EPI_KV, true><<<dim3(16, 32, 1), 256, 0, stream>>>(y_b, ckvw_b, 1024, 1024,
      nullptr, ca_vb, nullptr, nullptr, kt, vt, nullptr, nullptr);
  else     gemm_bt<EPI_KV, false><<<dim3(16, 32, 1), 256, 0, stream>>>(y, ca_kvw, 1024, 1024,
      nullptr, ca_vb, nullptr, nullptr, kt, vt, nullptr, nullptr);
  attn_kernel<true><<<dim3(17, NHEAD, 8), 256, 0, stream>>>(qt, kt, vt, ca_rpb, opart, mlf);
  attn_combine_kernel<<<dim3(NROWS / 32), 256, 0, stream>>>(opart, mlf, hln);
  if (asy) gemm_bt<EPI_RES, true><<<dim3(8, 33, 1), 256, 0, stream>>>(hln, cpw_b, 1024, 1024,
      ca_pb, nullptr, g2, xf, nullptr, nullptr, nullptr, nullptr);
  else     gemm_bt<EPI_RES, false><<<dim3(8, 33, 1), 256, 0, stream>>>(hln, ca_pw, 1024, 1024,
      ca_pb, nullptr, g2, xf, nullptr, nullptr, nullptr, nullptr);

  // --- FFN ---
  ln_kernel<false><<<MACT, 256, 0, stream>>>(xf, nullptr, hln, n3g, n3b);
  if (asy) gemm_bt<EPI_GELU, true><<<dim3(32, 33, 1), 256, 0, stream>>>(hln, fc1w_b, 1024, 1024,
      fc1_b, nullptr, nullptr, nullptr, h1, nullptr, nullptr, nullptr);
  else     gemm_bt<EPI_GELU, false><<<dim3(32, 33, 1), 256, 0, stream>>>(hln, fc1_w, 1024, 1024,
      fc1_b, nullptr, nullptr, nullptr, h1, nullptr, nullptr, nullptr);
  if (asy) {
    // split-K=2, plain partial stores (z=0 -> part0, z=1 -> outf), then combine
    gemm_bt<EPI_PART, true><<<dim3(8, 33, 2), 256, 0, stream>>>(h1, fc2w_b, 4096, 2048,
        nullptr, nullptr, nullptr, part0, nullptr, nullptr, nullptr, outf);
    fc2_reduce_kernel<<<dim3(4100), 256, 0, stream>>>(part0, xf, fc2_b, g3, outf);
  } else {
    hipMemsetAsync(outf, 0, (size_t)MACT * EDIM * 4, stream);  // reset for final
    gemm_bt<EPI_FINAL, false><<<dim3(8, 33, 4), 256, 0, stream>>>(h1, fc2_w, 4096, 1024,
        fc2_b, nullptr, g3, xf, nullptr, nullptr, nullptr, outf);
  }
}